// Round 7
// baseline (198.649 us; speedup 1.0000x reference)
//
#include <hip/hip_runtime.h>

typedef unsigned short u16;
typedef __attribute__((ext_vector_type(4))) float f32x4;
typedef __attribute__((ext_vector_type(8))) __bf16 bf16x8;
typedef __attribute__((ext_vector_type(8))) unsigned short us8;

#define NN (2048ull*2048ull)

__device__ __forceinline__ u16 f2b(float x){
  union { float f; unsigned u; } v; v.f = x;
  unsigned r = v.u + 0x7FFFu + ((v.u >> 16) & 1u);
  return (u16)(r >> 16);
}
__device__ __forceinline__ float b2f(u16 x){
  union { unsigned u; float f; } v; v.u = ((unsigned)x) << 16; return v.f;
}

// ---------------- fused 3-way mix of A -> A1 (row-major) + A2T, BT (transposed), bf16
//                  block(0,0) also zero-inits deg1/deg2/rowsum (replaces memset) -------
__global__ __launch_bounds__(256)
void k_mix(const float* __restrict__ A,
           const float* __restrict__ w1, const float* __restrict__ w2,
           const float* __restrict__ wl,
           u16* __restrict__ A1, u16* __restrict__ A2T, u16* __restrict__ BT,
           float* __restrict__ zbuf){
  __shared__ u16 lt[4][64][72];
  const int t = threadIdx.x;
  if (blockIdx.x == 0 && blockIdx.y == 0){
    #pragma unroll
    for (int i=0;i<48;i++) zbuf[i*256 + t] = 0.f;   // deg1,deg2,rowsum = 12288 floats
  }
  const int mq = t & 15, nr = t >> 4;
  const int n0 = blockIdx.y * 64, m0 = blockIdx.x * 64;
  float f[3][2][5];
  #pragma unroll
  for (int s=0;s<3;s++){
    const float* w = (s==0) ? w1 : (s==1) ? w2 : wl;
    #pragma unroll
    for (int c=0;c<2;c++){
      float m = -1e30f;
      #pragma unroll
      for (int e=0;e<5;e++) m = fmaxf(m, w[e*2+c]);
      float sum = 0.f;
      #pragma unroll
      for (int e=0;e<5;e++){ f[s][c][e] = __expf(w[e*2+c]-m); sum += f[s][c][e]; }
      float inv = 1.f/sum;
      #pragma unroll
      for (int e=0;e<5;e++) f[s][c][e] *= inv;
    }
  }

  #pragma unroll
  for (int rr=0; rr<4; ++rr){
    const int nl = nr*4 + rr;
    const size_t off = (size_t)(n0+nl)*2048 + m0 + mq*4;
    float4 a0 = *(const float4*)&A[off];
    float4 a1 = *(const float4*)&A[NN + off];
    float4 a2 = *(const float4*)&A[2*NN + off];
    float4 a3 = *(const float4*)&A[3*NN + off];
    float4 a4 = *(const float4*)&A[4*NN + off];
    float ax[4][5] = {{a0.x,a1.x,a2.x,a3.x,a4.x},
                      {a0.y,a1.y,a2.y,a3.y,a4.y},
                      {a0.z,a1.z,a2.z,a3.z,a4.z},
                      {a0.w,a1.w,a2.w,a3.w,a4.w}};
    #pragma unroll
    for (int c=0;c<2;c++){
      ushort4 o1, o2, o3;
      #pragma unroll
      for (int j=0;j<4;j++){
        float s1=0.f,s2=0.f,s3=0.f;
        #pragma unroll
        for (int e=0;e<5;e++){
          s1 += ax[j][e]*f[0][c][e];
          s2 += ax[j][e]*f[1][c][e];
          s3 += ax[j][e]*f[2][c][e];
        }
        ((u16*)&o1)[j] = f2b(s1);
        ((u16*)&o2)[j] = f2b(s2);
        ((u16*)&o3)[j] = f2b(s3);
      }
      *(ushort4*)&A1[(size_t)c*NN + off] = o1;
      *(ushort4*)&lt[c][nl][mq*4] = o2;
      *(ushort4*)&lt[2+c][nl][mq*4] = o3;
    }
  }
  __syncthreads();
  const int nq = t & 15, mr = t >> 4;
  #pragma unroll
  for (int s=0;s<4;s++){
    u16* __restrict__ dst = (s<2) ? A2T : BT;
    const int c = s & 1;
    #pragma unroll
    for (int rr=0;rr<4;rr++){
      const int ml = mr*4 + rr;
      ushort4 o;
      o.x = lt[s][nq*4+0][ml];
      o.y = lt[s][nq*4+1][ml];
      o.z = lt[s][nq*4+2][ml];
      o.w = lt[s][nq*4+3][ml];
      *(ushort4*)&dst[(size_t)c*NN + (size_t)(m0+ml)*2048 + n0 + nq*4] = o;
    }
  }
}

// ------- big bt-GEMM, 256x128 tile, 4 waves x (128x64 wave tile), 3-deep counted-vmcnt
//         pipeline, XOR-swizzled LDS. C = A @ Bt^T (bf16 out) + fused column sums.
//         TRANS: store C^T. ------------------------------------------------------------
template<bool TRANS>
__global__ __launch_bounds__(256, 1)
void k_gemm_big(const u16* __restrict__ A, const u16* __restrict__ Bt,
                u16* __restrict__ C, float* __restrict__ deg){
  __shared__ u16 lA[3][256*64];   // 96 KB
  __shared__ u16 lB[3][128*64];   // 48 KB
  const int tid = threadIdx.x;
  const int bm = blockIdx.x, bn = blockIdx.y, cc = blockIdx.z;
  const u16* __restrict__ Ab = A + (size_t)cc*NN + (size_t)(bm*256)*2048;
  const u16* __restrict__ Bb = Bt + (size_t)cc*NN + (size_t)(bn*128)*2048;
  const int wid = tid >> 6, lane = tid & 63;
  const int wr = wid >> 1, wc = wid & 1;          // wave tile: 128 rows x 64 cols
  const int fl = lane & 15, fkg = lane >> 4;
  // staging: 256 threads cover 32 rows x 8 chunks of 16B per load
  const int srow = tid >> 3;                       // 0..31
  const int scol_sw = ((tid & 7) ^ (srow & 7)) << 3;

  f32x4 acc[8][4];
  const f32x4 zero = {0.f,0.f,0.f,0.f};
  #pragma unroll
  for (int i=0;i<8;i++)
    #pragma unroll
    for (int jj=0;jj<4;jj++) acc[i][jj] = zero;

  auto stage = [&](int buf, int k0){
    #pragma unroll
    for (int i=0;i<8;++i)
      __builtin_amdgcn_global_load_lds(
        (const __attribute__((address_space(1))) void*)(Ab + (size_t)(i*32 + srow)*2048 + k0 + scol_sw),
        (__attribute__((address_space(3))) void*)(&lA[buf][(i*32 + (wid<<3))*64]), 16, 0, 0);
    #pragma unroll
    for (int i=0;i<4;++i)
      __builtin_amdgcn_global_load_lds(
        (const __attribute__((address_space(1))) void*)(Bb + (size_t)(i*32 + srow)*2048 + k0 + scol_sw),
        (__attribute__((address_space(3))) void*)(&lB[buf][(i*32 + (wid<<3))*64]), 16, 0, 0);
  };

  auto compute = [&](const u16* __restrict__ ca, const u16* __restrict__ cb){
    #pragma unroll
    for (int ks=0; ks<2; ++ks){
      const int csw = (((ks*4 + fkg) ^ (fl & 7)) << 3);
      bf16x8 af[8], bfr[4];
      #pragma unroll
      for (int mi=0;mi<8;mi++)
        af[mi] = *reinterpret_cast<const bf16x8*>(&ca[(wr*128 + mi*16 + fl)*64 + csw]);
      #pragma unroll
      for (int ni=0;ni<4;ni++)
        bfr[ni] = *reinterpret_cast<const bf16x8*>(&cb[(wc*64 + ni*16 + fl)*64 + csw]);
      __builtin_amdgcn_sched_barrier(0);
      __builtin_amdgcn_s_setprio(1);
      #pragma unroll
      for (int mi=0;mi<8;mi++)
        #pragma unroll
        for (int ni=0;ni<4;ni++)
          acc[mi][ni] = __builtin_amdgcn_mfma_f32_16x16x32_bf16(af[mi], bfr[ni], acc[mi][ni], 0, 0, 0);
      __builtin_amdgcn_s_setprio(0);
      __builtin_amdgcn_sched_barrier(0);
    }
  };

  // prologue: 3 tiles in flight
  stage(0, 0);
  stage(1, 64);
  stage(2, 128);
  int cur = 0;
  for (int t = 0; t < 29; ++t){
    asm volatile("s_waitcnt vmcnt(24)" ::: "memory");  // tile t landed; t+1,t+2 in flight
    __builtin_amdgcn_sched_barrier(0);
    __builtin_amdgcn_s_barrier();
    __builtin_amdgcn_sched_barrier(0);
    compute(&lA[cur][0], &lB[cur][0]);
    __builtin_amdgcn_s_barrier();                      // all waves done reading buf[cur]
    __builtin_amdgcn_sched_barrier(0);
    stage(cur, (t+3)*64);                              // refill buf[cur] with tile t+3
    cur = (cur == 2) ? 0 : cur + 1;
  }
  // t = 29, 30, 31 (no further staging)
  asm volatile("s_waitcnt vmcnt(24)" ::: "memory");
  __builtin_amdgcn_sched_barrier(0);
  __builtin_amdgcn_s_barrier();
  __builtin_amdgcn_sched_barrier(0);
  compute(&lA[cur][0], &lB[cur][0]);
  cur = (cur == 2) ? 0 : cur + 1;
  asm volatile("s_waitcnt vmcnt(12)" ::: "memory");
  __builtin_amdgcn_sched_barrier(0);
  __builtin_amdgcn_s_barrier();
  __builtin_amdgcn_sched_barrier(0);
  compute(&lA[cur][0], &lB[cur][0]);
  cur = (cur == 2) ? 0 : cur + 1;
  asm volatile("s_waitcnt vmcnt(0)" ::: "memory");
  __builtin_amdgcn_sched_barrier(0);
  __builtin_amdgcn_s_barrier();
  __builtin_amdgcn_sched_barrier(0);
  compute(&lA[cur][0], &lB[cur][0]);

  // fused column sums: deg[c][col] += sum over this wave's 128 rows
  #pragma unroll
  for (int ni=0; ni<4; ++ni){
    float cs = 0.f;
    #pragma unroll
    for (int mi=0;mi<8;mi++)
      #pragma unroll
      for (int r=0;r<4;r++) cs += acc[mi][ni][r];
    cs += __shfl_xor(cs, 16);
    cs += __shfl_xor(cs, 32);
    if (lane < 16)
      atomicAdd(&deg[cc*2048 + bn*128 + wc*64 + ni*16 + fl], cs);
  }
  const int rbase = fkg << 2;
  if (!TRANS){
    u16* __restrict__ Cb = C + (size_t)cc*NN + (size_t)(bm*256 + wr*128)*2048 + bn*128 + wc*64;
    #pragma unroll
    for (int mi=0;mi<8;mi++)
      #pragma unroll
      for (int ni=0;ni<4;ni++)
        #pragma unroll
        for (int r=0;r<4;r++)
          Cb[(size_t)(mi*16 + rbase + r)*2048 + ni*16 + fl] = f2b(acc[mi][ni][r]);
  } else {
    u16* __restrict__ Cb = C + (size_t)cc*NN + (size_t)(bn*128 + wc*64)*2048 + bm*256 + wr*128;
    #pragma unroll
    for (int ni=0;ni<4;ni++)
      #pragma unroll
      for (int mi=0;mi<8;mi++){
        ushort4 o;
        o.x = f2b(acc[mi][ni][0]); o.y = f2b(acc[mi][ni][1]);
        o.z = f2b(acc[mi][ni][2]); o.w = f2b(acc[mi][ni][3]);
        *(ushort4*)&Cb[(size_t)(ni*16 + fl)*2048 + mi*16 + rbase] = o;
      }
  }
}

// ---------------- BT *= dinv1[k] in place ----------------
__global__ void k_btscale(u16* __restrict__ BT, const float* __restrict__ deg){
  size_t idx = (size_t)blockIdx.x*256 + threadIdx.x;   // 2*NN/8 = 1,048,576 total
  int c  = (int)(idx >> 19);
  int k8 = ((int)(idx & 255)) * 8;
  us8 v = ((const us8*)BT)[idx];
  #pragma unroll
  for (int j=0;j<8;j++){
    float d = deg[c*2048 + k8 + j];
    float di = d > 0.f ? 1.f/d : 0.f;
    v[j] = f2b(b2f(v[j]) * di);
  }
  ((us8*)BT)[idx] = v;
}

// -------- rowsum[c][n] = sum_m HT[c][m][n] * dinv2[c][m]  (dout source) ---------------
__global__ __launch_bounds__(256)
void k_wcolsum(const u16* __restrict__ HT, const float* __restrict__ deg2,
               float* __restrict__ rowsum){
  __shared__ float sdi[128];
  const int t = threadIdx.x;
  const int n = blockIdx.x * 256 + t;
  const int m0 = blockIdx.y * 128;
  const int c = blockIdx.z;
  if (t < 128){
    float d = deg2[c*2048 + m0 + t];
    sdi[t] = d > 0.f ? 1.f/d : 0.f;
  }
  __syncthreads();
  const u16* __restrict__ p = HT + (size_t)c*NN + (size_t)m0*2048 + n;
  float s = 0.f;
  #pragma unroll 4
  for (int m=0;m<128;m++)
    s += b2f(p[(size_t)m*2048]) * sdi[m];
  atomicAdd(&rowsum[c*2048 + n], s);
}

// ---------------- hw = h @ gcn_w  (f32), 128 blocks x 16 rows ----------------
__global__ __launch_bounds__(256)
void k_hw(const float* __restrict__ h, const float* __restrict__ W, float* __restrict__ hw){
  __shared__ float lh[16][256];
  int t = threadIdx.x;
  int n0 = blockIdx.x * 16;
  for (int idx = t; idx < 16*256; idx += 256)
    lh[idx >> 8][idx & 255] = h[(size_t)(n0 + (idx>>8))*256 + (idx&255)];
  __syncthreads();
  int d = t & 127, half = t >> 7;
  float acc[8];
  #pragma unroll
  for (int nn=0;nn<8;nn++) acc[nn] = 0.f;
  for (int k=0;k<256;k++){
    float wv = W[(size_t)k*128 + d];
    #pragma unroll
    for (int nn=0;nn<8;nn++) acc[nn] += lh[half*8+nn][k]*wv;
  }
  #pragma unroll
  for (int nn=0;nn<8;nn++) hw[(size_t)(n0 + half*8 + nn)*128 + d] = acc[nn];
}

// ---------------- PT[c][d][n] = bf16(rsqrt(max(rowsum,1)) * hw[n][d]) ----------------
__global__ void k_pt(const float* __restrict__ hw, const float* __restrict__ rowsum,
                     u16* __restrict__ PT){
  int t = threadIdx.x;
  int n = blockIdx.x * 64 + (t & 63);
  int c = blockIdx.y;
  float dv = rsqrtf(fmaxf(rowsum[c*2048 + n], 1.0f));
  for (int d = t >> 6; d < 128; d += 4)
    PT[((size_t)c*128 + d)*2048 + n] = f2b(dv * hw[(size_t)n*128 + d]);
}

// ------- GEMM3 split-K=8 (2-barrier loop), partial f32 buffers: aggp = HT @ PT^T ------
__global__ __launch_bounds__(256, 2)
void k_gemm3(const u16* __restrict__ A, const u16* __restrict__ Bt, float* __restrict__ Cp){
  __shared__ u16 lA[128*64];
  __shared__ u16 lB[128*64];
  const int tid = threadIdx.x;
  const int bm = blockIdx.x, bk = blockIdx.y, cc = blockIdx.z;
  const u16* __restrict__ Ab = A + (size_t)cc*NN + (size_t)(bm*128)*2048 + bk*256;
  const u16* __restrict__ Bb = Bt + (size_t)cc*(128*2048) + bk*256;
  float* __restrict__ Cb = Cp + ((size_t)bk*2 + cc)*2048*128 + (size_t)(bm*128)*128;
  const int wid = tid >> 6, lane = tid & 63;
  const int wr = wid >> 1, wc = wid & 1;
  const int fl = lane & 15, fk = (lane >> 4) << 3;
  const int srow = (wid << 3) + (lane >> 3);
  const int scol = (lane & 7) << 3;

  f32x4 acc[4][4];
  const f32x4 zero = {0.f,0.f,0.f,0.f};
  #pragma unroll
  for (int i=0;i<4;i++)
    #pragma unroll
    for (int jj=0;jj<4;jj++) acc[i][jj] = zero;

  for (int k0 = 0; k0 < 256; k0 += 64){
    #pragma unroll
    for (int it = 0; it < 4; ++it){
      int r = it*32 + srow;
      __builtin_amdgcn_global_load_lds(
        (const __attribute__((address_space(1))) void*)(Ab + (size_t)r*2048 + k0 + scol),
        (__attribute__((address_space(3))) void*)(&lA[(it*32 + (wid<<3))*64]), 16, 0, 0);
      __builtin_amdgcn_global_load_lds(
        (const __attribute__((address_space(1))) void*)(Bb + (size_t)r*2048 + k0 + scol),
        (__attribute__((address_space(3))) void*)(&lB[(it*32 + (wid<<3))*64]), 16, 0, 0);
    }
    __syncthreads();
    #pragma unroll
    for (int ks = 0; ks < 2; ++ks){
      bf16x8 af[4], bfr[4];
      #pragma unroll
      for (int mi=0;mi<4;mi++)
        af[mi] = *reinterpret_cast<const bf16x8*>(&lA[(wr*64 + mi*16 + fl)*64 + ks*32 + fk]);
      #pragma unroll
      for (int ni=0;ni<4;ni++)
        bfr[ni] = *reinterpret_cast<const bf16x8*>(&lB[(wc*64 + ni*16 + fl)*64 + ks*32 + fk]);
      #pragma unroll
      for (int mi=0;mi<4;mi++)
        #pragma unroll
        for (int ni=0;ni<4;ni++)
          acc[mi][ni] = __builtin_amdgcn_mfma_f32_16x16x32_bf16(af[mi], bfr[ni], acc[mi][ni], 0, 0, 0);
    }
    __syncthreads();
  }
  const int rbase = (lane >> 4) << 2;
  #pragma unroll
  for (int mi=0;mi<4;mi++)
    #pragma unroll
    for (int ni=0;ni<4;ni++)
      #pragma unroll
      for (int r=0;r<4;r++)
        Cb[(size_t)(wr*64 + mi*16 + rbase + r)*128 + wc*64 + ni*16 + fl] = acc[mi][ni][r];
}

// -------- head: Xc = relu(dinv2[c,m] * sum_p aggp + gb); out = relu(Xc@W1+b1)@W2+b2 ---
// 128 blocks x 16 rows
__global__ __launch_bounds__(256)
void k_head(const float* __restrict__ aggp, const float* __restrict__ deg2,
            const float* __restrict__ gb,
            const float* __restrict__ W1, const float* __restrict__ b1,
            const float* __restrict__ W2, const float* __restrict__ b2,
            float* __restrict__ out){
  __shared__ float lx[16][256];
  __shared__ float lt[16][132];
  int t = threadIdx.x;
  int n0 = blockIdx.x * 16;
  for (int idx = t; idx < 1024; idx += 256){
    int row = idx >> 6;
    int q = idx & 63;
    int c = q >> 5, d4 = (q & 31) * 4;
    float dg = deg2[c*2048 + n0 + row];
    float di = dg > 0.f ? 1.f/dg : 0.f;
    float4 s = {0.f,0.f,0.f,0.f};
    #pragma unroll
    for (int p=0;p<8;p++){
      const float4 v = *(const float4*)&aggp[(((size_t)p*2 + c)*2048 + n0 + row)*128 + d4];
      s.x += v.x; s.y += v.y; s.z += v.z; s.w += v.w;
    }
    const float4 bv = *(const float4*)&gb[d4];
    s.x = fmaxf(s.x*di + bv.x, 0.f); s.y = fmaxf(s.y*di + bv.y, 0.f);
    s.z = fmaxf(s.z*di + bv.z, 0.f); s.w = fmaxf(s.w*di + bv.w, 0.f);
    *(float4*)&lx[row][c*128 + d4] = s;
  }
  __syncthreads();
  int d = t & 127, half = t >> 7;
  float acc[8];
  #pragma unroll
  for (int nn=0;nn<8;nn++) acc[nn] = 0.f;
  for (int k=0;k<256;k++){
    float wv = W1[(size_t)k*128 + d];
    #pragma unroll
    for (int nn=0;nn<8;nn++) acc[nn] += lx[half*8+nn][k]*wv;
  }
  float bb = b1[d];
  #pragma unroll
  for (int nn=0;nn<8;nn++){
    float v = acc[nn] + bb;
    lt[half*8+nn][d] = v > 0.f ? v : 0.f;
  }
  __syncthreads();
  {
    int row = t >> 4, q = t & 15;
    float s = b2[q];
    for (int dd=0; dd<128; dd++) s += lt[row][dd] * W2[(size_t)dd*16 + q];
    out[(size_t)(n0+row)*16 + q] = s;
  }
}

extern "C" void kernel_launch(void* const* d_in, const int* in_sizes, int n_in,
                              void* d_out, int out_size, void* d_ws, size_t ws_size,
                              hipStream_t stream){
  const float* A   = (const float*)d_in[0];
  const float* h   = (const float*)d_in[1];
  const float* w1  = (const float*)d_in[2];
  const float* w2  = (const float*)d_in[3];
  const float* wl  = (const float*)d_in[4];
  const float* gw  = (const float*)d_in[5];
  const float* gb  = (const float*)d_in[6];
  const float* l1w = (const float*)d_in[7];
  const float* l1b = (const float*)d_in[8];
  const float* l2w = (const float*)d_in[9];
  const float* l2b = (const float*)d_in[10];
  float* out = (float*)d_out;
  char* ws = (char*)d_ws;

  const size_t SZ = 2*NN*2;   // 16.78 MB (one bf16 [2][2048][2048])
  u16*  A1   = (u16*)(ws);
  u16*  A2T  = (u16*)(ws + 1*SZ);
  u16*  BT   = (u16*)(ws + 2*SZ);
  u16*  Hbf  = (u16*)(ws + 3*SZ);
  u16*  HT   = (u16*)(ws + 4*SZ);        // H2^T, raw (dinv2 NOT applied)
  float* aggp= (float*)(ws + 5*SZ);      // 8 x 2 x 2048 x 128 f32 = 16.78MB
  char* tail = ws + 6*SZ;
  float* hw    = (float*)tail;                    // 1MB
  u16*  PT     = (u16*)(tail + 2048*128*4);       // 1MB
  float* deg1  = (float*)(tail + 2048*128*4 + 2*128*2048*2);
  float* deg2  = deg1 + 4096;
  float* rowsum= deg2 + 4096;

  const size_t TOTAL = 6*SZ + 2048*128*4 + (size_t)2*128*2048*2 + 3*4096*4;
  if (ws_size < TOTAL){ hipMemsetAsync(d_out, 0, (size_t)out_size*4, stream); return; }

  // deg1/deg2/rowsum zeroed inside k_mix (block 0,0); no memset dispatch
  k_mix<<<dim3(32,32), 256, 0, stream>>>(A, w1, w2, wl, A1, A2T, BT, deg1);
  // H = A1 @ A2  (bf16 out, colsum -> deg1)
  k_gemm_big<false><<<dim3(8,16,2), 256, 0, stream>>>(A1, A2T, Hbf, deg1);
  // fold dinv1 into B operand
  k_btscale<<<4096, 256, 0, stream>>>(BT, deg1);
  // H2^T = (H @ B')^T directly (bf16 out, colsum -> deg2)
  k_gemm_big<true><<<dim3(8,16,2), 256, 0, stream>>>(Hbf, BT, HT, deg2);
  // dout source: rowsum[c][n] = sum_m HT[c][m][n]*dinv2[c][m]
  k_wcolsum<<<dim3(8,16,2), 256, 0, stream>>>(HT, deg2, rowsum);
  k_hw<<<128, 256, 0, stream>>>(h, gw, hw);
  k_pt<<<dim3(32,2), 256, 0, stream>>>(hw, rowsum, PT);
  // agg partials (split-K = 8) on RAW HT; dinv2 applied in k_head
  k_gemm3<<<dim3(16,8,2), 256, 0, stream>>>(HT, PT, aggp);
  k_head<<<128, 256, 0, stream>>>(aggp, deg2, gb, l1w, l1b, l2w, l2b, out);
}

// Round 8
// 165.371 us; speedup vs baseline: 1.2012x; 1.2012x over previous
//
#include <hip/hip_runtime.h>

typedef unsigned short u16;
typedef __attribute__((ext_vector_type(4))) float f32x4;
typedef __attribute__((ext_vector_type(8))) __bf16 bf16x8;
typedef __attribute__((ext_vector_type(8))) unsigned short us8;

#define NN (2048ull*2048ull)

__device__ __forceinline__ u16 f2b(float x){
  union { float f; unsigned u; } v; v.f = x;
  unsigned r = v.u + 0x7FFFu + ((v.u >> 16) & 1u);
  return (u16)(r >> 16);
}
__device__ __forceinline__ float b2f(u16 x){
  union { unsigned u; float f; } v; v.u = ((unsigned)x) << 16; return v.f;
}

// ---- fused 3-way mix of A -> A1T, A2T, BT (all transposed bf16 [2][2048][2048])
//      + fused row-sums of A1T (=colsum A1 -> sA1) and BT (=colsum B -> deg2) ---------
__global__ __launch_bounds__(256)
void k_mix(const float* __restrict__ A,
           const float* __restrict__ w1, const float* __restrict__ w2,
           const float* __restrict__ wl,
           u16* __restrict__ A1T, u16* __restrict__ A2T, u16* __restrict__ BT,
           float* __restrict__ sA1, float* __restrict__ deg2){
  __shared__ u16 lt[6][64][72];
  const int t = threadIdx.x;
  const int mq = t & 15, nr = t >> 4;
  const int n0 = blockIdx.y * 64, m0 = blockIdx.x * 64;
  float f[3][2][5];
  #pragma unroll
  for (int s=0;s<3;s++){
    const float* w = (s==0) ? w1 : (s==1) ? w2 : wl;
    #pragma unroll
    for (int c=0;c<2;c++){
      float m = -1e30f;
      #pragma unroll
      for (int e=0;e<5;e++) m = fmaxf(m, w[e*2+c]);
      float sum = 0.f;
      #pragma unroll
      for (int e=0;e<5;e++){ f[s][c][e] = __expf(w[e*2+c]-m); sum += f[s][c][e]; }
      float inv = 1.f/sum;
      #pragma unroll
      for (int e=0;e<5;e++) f[s][c][e] *= inv;
    }
  }

  #pragma unroll
  for (int rr=0; rr<4; ++rr){
    const int nl = nr*4 + rr;
    const size_t off = (size_t)(n0+nl)*2048 + m0 + mq*4;
    float4 a0 = *(const float4*)&A[off];
    float4 a1 = *(const float4*)&A[NN + off];
    float4 a2 = *(const float4*)&A[2*NN + off];
    float4 a3 = *(const float4*)&A[3*NN + off];
    float4 a4 = *(const float4*)&A[4*NN + off];
    float ax[4][5] = {{a0.x,a1.x,a2.x,a3.x,a4.x},
                      {a0.y,a1.y,a2.y,a3.y,a4.y},
                      {a0.z,a1.z,a2.z,a3.z,a4.z},
                      {a0.w,a1.w,a2.w,a3.w,a4.w}};
    #pragma unroll
    for (int c=0;c<2;c++){
      ushort4 o1, o2, o3;
      #pragma unroll
      for (int j=0;j<4;j++){
        float s1=0.f,s2=0.f,s3=0.f;
        #pragma unroll
        for (int e=0;e<5;e++){
          s1 += ax[j][e]*f[0][c][e];
          s2 += ax[j][e]*f[1][c][e];
          s3 += ax[j][e]*f[2][c][e];
        }
        ((u16*)&o1)[j] = f2b(s1);
        ((u16*)&o2)[j] = f2b(s2);
        ((u16*)&o3)[j] = f2b(s3);
      }
      *(ushort4*)&lt[0+c][nl][mq*4] = o1;
      *(ushort4*)&lt[2+c][nl][mq*4] = o2;
      *(ushort4*)&lt[4+c][nl][mq*4] = o3;
    }
  }
  __syncthreads();
  const int nq = t & 15, mr = t >> 4;
  #pragma unroll
  for (int s=0;s<6;s++){
    u16* __restrict__ dst = (s<2) ? A1T : (s<4) ? A2T : BT;
    const int c = s & 1;
    #pragma unroll
    for (int rr=0;rr<4;rr++){
      const int ml = mr*4 + rr;
      ushort4 o;
      o.x = lt[s][nq*4+0][ml];
      o.y = lt[s][nq*4+1][ml];
      o.z = lt[s][nq*4+2][ml];
      o.w = lt[s][nq*4+3][ml];
      *(ushort4*)&dst[(size_t)c*NN + (size_t)(m0+ml)*2048 + n0 + nq*4] = o;
      if (s < 2 || s >= 4){
        float part = b2f(o.x)+b2f(o.y)+b2f(o.z)+b2f(o.w);
        part += __shfl_xor(part, 1); part += __shfl_xor(part, 2);
        part += __shfl_xor(part, 4); part += __shfl_xor(part, 8);
        if (nq == 0){
          float* tgt = (s < 2) ? sA1 : deg2;
          atomicAdd(&tgt[c*2048 + m0 + ml], part);
        }
      }
    }
  }
}

// ---- deg1[c][j] = sum_k sA1[c][k] * A2T[c][j][k]  (one wave per row) -----------------
__global__ __launch_bounds__(256)
void k_deg1(const u16* __restrict__ A2T, const float* __restrict__ sA1,
            float* __restrict__ deg1){
  const int g = blockIdx.x*4 + (threadIdx.x >> 6);
  const int lane = threadIdx.x & 63;
  const int c = g >> 11, j = g & 2047;
  const u16* __restrict__ row = A2T + (size_t)c*NN + (size_t)j*2048;
  const float* __restrict__ sv = sA1 + c*2048;
  float s = 0.f;
  #pragma unroll
  for (int it=0; it<4; ++it){
    const int k = it*512 + lane*8;
    us8 v = *(const us8*)&row[k];
    const float4 f0 = *(const float4*)&sv[k];
    const float4 f1 = *(const float4*)&sv[k+4];
    s += b2f(v[0])*f0.x + b2f(v[1])*f0.y + b2f(v[2])*f0.z + b2f(v[3])*f0.w
       + b2f(v[4])*f1.x + b2f(v[5])*f1.y + b2f(v[6])*f1.z + b2f(v[7])*f1.w;
  }
  s += __shfl_xor(s, 1);  s += __shfl_xor(s, 2);  s += __shfl_xor(s, 4);
  s += __shfl_xor(s, 8);  s += __shfl_xor(s, 16); s += __shfl_xor(s, 32);
  if (lane == 0) deg1[c*2048 + j] = s;
}

// ---- weighted column-sum over rows of MT: outv[c][n] += sum_m w[m]*MT[c][m][n] -------
// MODE 0: w = inv(va[m])        (va = deg2)
// MODE 1: w = inv(va[m])*vb[m]  (va = deg1, vb = v1)
// MODE 2: w = va[m]             (va = v3)
template<int MODE>
__global__ __launch_bounds__(256)
void k_wsum(const u16* __restrict__ MT, const float* __restrict__ va,
            const float* __restrict__ vb, float* __restrict__ outv){
  __shared__ float w[128];
  const int t = threadIdx.x;
  const int n = blockIdx.x * 256 + t;
  const int m0 = blockIdx.y * 128;
  const int c = blockIdx.z;
  if (t < 128){
    const int m = c*2048 + m0 + t;
    float x;
    if (MODE == 0){ float d = va[m]; x = d > 0.f ? 1.f/d : 0.f; }
    else if (MODE == 1){ float d = va[m]; x = (d > 0.f ? 1.f/d : 0.f) * vb[m]; }
    else { x = va[m]; }
    w[t] = x;
  }
  __syncthreads();
  const u16* __restrict__ p = MT + (size_t)c*NN + (size_t)m0*2048 + n;
  float s = 0.f;
  #pragma unroll 4
  for (int m=0;m<128;m++)
    s += b2f(p[(size_t)m*2048]) * w[m];
  atomicAdd(&outv[c*2048 + n], s);
}

// ---------------- hw = h @ gcn_w  (f32), 128 blocks x 16 rows ----------------
__global__ __launch_bounds__(256)
void k_hw(const float* __restrict__ h, const float* __restrict__ W, float* __restrict__ hw){
  __shared__ float lh[16][256];
  int t = threadIdx.x;
  int n0 = blockIdx.x * 16;
  for (int idx = t; idx < 16*256; idx += 256)
    lh[idx >> 8][idx & 255] = h[(size_t)(n0 + (idx>>8))*256 + (idx&255)];
  __syncthreads();
  int d = t & 127, half = t >> 7;
  float acc[8];
  #pragma unroll
  for (int nn=0;nn<8;nn++) acc[nn] = 0.f;
  for (int k=0;k<256;k++){
    float wv = W[(size_t)k*128 + d];
    #pragma unroll
    for (int nn=0;nn<8;nn++) acc[nn] += lh[half*8+nn][k]*wv;
  }
  #pragma unroll
  for (int nn=0;nn<8;nn++) hw[(size_t)(n0 + half*8 + nn)*128 + d] = acc[nn];
}

// ---------------- PT[c][d][n] = bf16(rsqrt(max(rowsum,1)) * hw[n][d]) ----------------
__global__ void k_pt(const float* __restrict__ hw, const float* __restrict__ rowsum,
                     u16* __restrict__ PT){
  int t = threadIdx.x;
  int n = blockIdx.x * 64 + (t & 63);
  int c = blockIdx.y;
  float dv = rsqrtf(fmaxf(rowsum[c*2048 + n], 1.0f));
  for (int d = t >> 6; d < 128; d += 4)
    PT[((size_t)c*128 + d)*2048 + n] = f2b(dv * hw[(size_t)n*128 + d]);
}

// ------- thin bt-GEMM split-K=8 (2-barrier loop), f32 partials: Cp = A @ Bt^T ---------
__global__ __launch_bounds__(256, 2)
void k_gemm3(const u16* __restrict__ A, const u16* __restrict__ Bt, float* __restrict__ Cp){
  __shared__ u16 lA[128*64];
  __shared__ u16 lB[128*64];
  const int tid = threadIdx.x;
  const int bm = blockIdx.x, bk = blockIdx.y, cc = blockIdx.z;
  const u16* __restrict__ Ab = A + (size_t)cc*NN + (size_t)(bm*128)*2048 + bk*256;
  const u16* __restrict__ Bb = Bt + (size_t)cc*(128*2048) + bk*256;
  float* __restrict__ Cb = Cp + ((size_t)bk*2 + cc)*2048*128 + (size_t)(bm*128)*128;
  const int wid = tid >> 6, lane = tid & 63;
  const int wr = wid >> 1, wc = wid & 1;
  const int fl = lane & 15, fk = (lane >> 4) << 3;
  const int srow = (wid << 3) + (lane >> 3);
  const int scol = (lane & 7) << 3;

  f32x4 acc[4][4];
  const f32x4 zero = {0.f,0.f,0.f,0.f};
  #pragma unroll
  for (int i=0;i<4;i++)
    #pragma unroll
    for (int jj=0;jj<4;jj++) acc[i][jj] = zero;

  for (int k0 = 0; k0 < 256; k0 += 64){
    #pragma unroll
    for (int it = 0; it < 4; ++it){
      int r = it*32 + srow;
      __builtin_amdgcn_global_load_lds(
        (const __attribute__((address_space(1))) void*)(Ab + (size_t)r*2048 + k0 + scol),
        (__attribute__((address_space(3))) void*)(&lA[(it*32 + (wid<<3))*64]), 16, 0, 0);
      __builtin_amdgcn_global_load_lds(
        (const __attribute__((address_space(1))) void*)(Bb + (size_t)r*2048 + k0 + scol),
        (__attribute__((address_space(3))) void*)(&lB[(it*32 + (wid<<3))*64]), 16, 0, 0);
    }
    __syncthreads();
    #pragma unroll
    for (int ks = 0; ks < 2; ++ks){
      bf16x8 af[4], bfr[4];
      #pragma unroll
      for (int mi=0;mi<4;mi++)
        af[mi] = *reinterpret_cast<const bf16x8*>(&lA[(wr*64 + mi*16 + fl)*64 + ks*32 + fk]);
      #pragma unroll
      for (int ni=0;ni<4;ni++)
        bfr[ni] = *reinterpret_cast<const bf16x8*>(&lB[(wc*64 + ni*16 + fl)*64 + ks*32 + fk]);
      #pragma unroll
      for (int mi=0;mi<4;mi++)
        #pragma unroll
        for (int ni=0;ni<4;ni++)
          acc[mi][ni] = __builtin_amdgcn_mfma_f32_16x16x32_bf16(af[mi], bfr[ni], acc[mi][ni], 0, 0, 0);
    }
    __syncthreads();
  }
  const int rbase = (lane >> 4) << 2;
  #pragma unroll
  for (int mi=0;mi<4;mi++)
    #pragma unroll
    for (int ni=0;ni<4;ni++)
      #pragma unroll
      for (int r=0;r<4;r++)
        Cb[(size_t)(wr*64 + mi*16 + rbase + r)*128 + wc*64 + ni*16 + fl] = acc[mi][ni][r];
}

// ---- reduce 8 partials (+ optional dinv1 row scale) -> transposed bf16 QT[c][d][m] ---
template<bool SCALE>
__global__ __launch_bounds__(256)
void k_redt(const float* __restrict__ aggp, const float* __restrict__ deg1,
            u16* __restrict__ QT){
  __shared__ u16 lq[128][36];
  const int t = threadIdx.x;
  const int m0 = blockIdx.x * 32, c = blockIdx.y;
  const int d4 = (t & 31) * 4, mr = t >> 5;
  #pragma unroll
  for (int p4=0; p4<4; ++p4){
    const int m = m0 + p4*8 + mr;
    float4 s = {0.f,0.f,0.f,0.f};
    #pragma unroll
    for (int p=0;p<8;p++){
      const float4 v = *(const float4*)&aggp[(((size_t)p*2 + c)*2048 + m)*128 + d4];
      s.x += v.x; s.y += v.y; s.z += v.z; s.w += v.w;
    }
    if (SCALE){
      float dg = deg1[c*2048 + m];
      float di = dg > 0.f ? 1.f/dg : 0.f;
      s.x *= di; s.y *= di; s.z *= di; s.w *= di;
    }
    const int ml = p4*8 + mr;
    lq[d4+0][ml] = f2b(s.x); lq[d4+1][ml] = f2b(s.y);
    lq[d4+2][ml] = f2b(s.z); lq[d4+3][ml] = f2b(s.w);
  }
  __syncthreads();
  const int d = t >> 1, half = t & 1;
  u16* __restrict__ dst = QT + ((size_t)c*128 + d)*2048 + m0 + half*16;
  #pragma unroll
  for (int q=0;q<4;q++){
    ushort4 o;
    o.x = lq[d][half*16 + q*4 + 0];
    o.y = lq[d][half*16 + q*4 + 1];
    o.z = lq[d][half*16 + q*4 + 2];
    o.w = lq[d][half*16 + q*4 + 3];
    *(ushort4*)&dst[q*4] = o;
  }
}

// -------- head: Xc = relu(dinv2[c,m] * sum_p aggp + gb); out = relu(Xc@W1+b1)@W2+b2 ---
__global__ __launch_bounds__(256)
void k_head(const float* __restrict__ aggp, const float* __restrict__ deg2,
            const float* __restrict__ gb,
            const float* __restrict__ W1, const float* __restrict__ b1,
            const float* __restrict__ W2, const float* __restrict__ b2,
            float* __restrict__ out){
  __shared__ float lx[16][256];
  __shared__ float lt[16][132];
  int t = threadIdx.x;
  int n0 = blockIdx.x * 16;
  for (int idx = t; idx < 1024; idx += 256){
    int row = idx >> 6;
    int q = idx & 63;
    int c = q >> 5, d4 = (q & 31) * 4;
    float dg = deg2[c*2048 + n0 + row];
    float di = dg > 0.f ? 1.f/dg : 0.f;
    float4 s = {0.f,0.f,0.f,0.f};
    #pragma unroll
    for (int p=0;p<8;p++){
      const float4 v = *(const float4*)&aggp[(((size_t)p*2 + c)*2048 + n0 + row)*128 + d4];
      s.x += v.x; s.y += v.y; s.z += v.z; s.w += v.w;
    }
    const float4 bv = *(const float4*)&gb[d4];
    s.x = fmaxf(s.x*di + bv.x, 0.f); s.y = fmaxf(s.y*di + bv.y, 0.f);
    s.z = fmaxf(s.z*di + bv.z, 0.f); s.w = fmaxf(s.w*di + bv.w, 0.f);
    *(float4*)&lx[row][c*128 + d4] = s;
  }
  __syncthreads();
  int d = t & 127, half = t >> 7;
  float acc[8];
  #pragma unroll
  for (int nn=0;nn<8;nn++) acc[nn] = 0.f;
  for (int k=0;k<256;k++){
    float wv = W1[(size_t)k*128 + d];
    #pragma unroll
    for (int nn=0;nn<8;nn++) acc[nn] += lx[half*8+nn][k]*wv;
  }
  float bb = b1[d];
  #pragma unroll
  for (int nn=0;nn<8;nn++){
    float v = acc[nn] + bb;
    lt[half*8+nn][d] = v > 0.f ? v : 0.f;
  }
  __syncthreads();
  {
    int row = t >> 4, q = t & 15;
    float s = b2[q];
    for (int dd=0; dd<128; dd++) s += lt[row][dd] * W2[(size_t)dd*16 + q];
    out[(size_t)(n0+row)*16 + q] = s;
  }
}

extern "C" void kernel_launch(void* const* d_in, const int* in_sizes, int n_in,
                              void* d_out, int out_size, void* d_ws, size_t ws_size,
                              hipStream_t stream){
  const float* A   = (const float*)d_in[0];
  const float* h   = (const float*)d_in[1];
  const float* w1  = (const float*)d_in[2];
  const float* w2  = (const float*)d_in[3];
  const float* wl  = (const float*)d_in[4];
  const float* gw  = (const float*)d_in[5];
  const float* gb  = (const float*)d_in[6];
  const float* l1w = (const float*)d_in[7];
  const float* l1b = (const float*)d_in[8];
  const float* l2w = (const float*)d_in[9];
  const float* l2b = (const float*)d_in[10];
  float* out = (float*)d_out;
  char* ws = (char*)d_ws;

  const size_t SZ = 2*NN*2;     // 16.78 MB (one bf16 [2][2048][2048])
  u16*  A1T  = (u16*)(ws);
  u16*  A2T  = (u16*)(ws + 1*SZ);
  u16*  BT   = (u16*)(ws + 2*SZ);
  float* aggp= (float*)(ws + 3*SZ);               // 8 x 2 x 2048 x 128 f32 = 16.78MB
  char* tail = ws + 4*SZ;
  float* hw    = (float*)tail;                    // 1MB
  u16*  PT     = (u16*)(tail + 1048576);          // 1MB
  u16*  Q1T    = (u16*)(tail + 2*1048576);        // 1MB
  u16*  Q2T    = (u16*)(tail + 3*1048576);        // 1MB
  float* sA1   = (float*)(tail + 4*1048576);      // 6 vectors x 2ch x 2048 f32
  float* deg1  = sA1 + 4096;
  float* deg2  = deg1 + 4096;
  float* v1    = deg2 + 4096;
  float* v3    = v1 + 4096;
  float* rowsum= v3 + 4096;

  const size_t TOTAL = 4*SZ + 4*1048576 + 6*4096*4;
  if (ws_size < TOTAL){ hipMemsetAsync(d_out, 0, (size_t)out_size*4, stream); return; }

  // zero atomics targets: sA1, deg1(harmless), deg2, v1, v3, rowsum
  hipMemsetAsync(sA1, 0, 6*4096*4, stream);

  // A -> A1T, A2T, BT + sA1 (colsum A1), deg2 (colsum B)
  k_mix<<<dim3(32,32), 256, 0, stream>>>(A, w1, w2, wl, A1T, A2T, BT, sA1, deg2);
  // deg1 = sA1 @ A2 (row-dot over A2T)
  k_deg1<<<1024, 256, 0, stream>>>(A2T, sA1, deg1);
  // rowsum chain: v1 = B@dinv2 ; v3 = A2@(dinv1*v1) ; rowsum = A1@v3
  k_wsum<0><<<dim3(8,16,2), 256, 0, stream>>>(BT, deg2, deg2, v1);
  k_wsum<1><<<dim3(8,16,2), 256, 0, stream>>>(A2T, deg1, v1, v3);
  k_wsum<2><<<dim3(8,16,2), 256, 0, stream>>>(A1T, v3, v3, rowsum);
  // features
  k_hw<<<128, 256, 0, stream>>>(h, gw, hw);
  k_pt<<<dim3(32,2), 256, 0, stream>>>(hw, rowsum, PT);
  // agg chain: Q1 = A1^T@P ; Q2 = dinv1*(A2^T@Q1) ; Q3 = B^T@Q2 ; (dinv2 in head)
  k_gemm3<<<dim3(16,8,2), 256, 0, stream>>>(A1T, PT, aggp);
  k_redt<false><<<dim3(64,2), 256, 0, stream>>>(aggp, deg1, Q1T);
  k_gemm3<<<dim3(16,8,2), 256, 0, stream>>>(A2T, Q1T, aggp);
  k_redt<true><<<dim3(64,2), 256, 0, stream>>>(aggp, deg1, Q2T);
  k_gemm3<<<dim3(16,8,2), 256, 0, stream>>>(BT, Q2T, aggp);
  k_head<<<128, 256, 0, stream>>>(aggp, deg2, gb, l1w, l1b, l2w, l2b, out);
}

// Round 9
// 164.139 us; speedup vs baseline: 1.2102x; 1.0075x over previous
//
#include <hip/hip_runtime.h>

typedef unsigned short u16;
typedef __attribute__((ext_vector_type(4))) float f32x4;
typedef __attribute__((ext_vector_type(8))) __bf16 bf16x8;
typedef __attribute__((ext_vector_type(8))) unsigned short us8;

#define NN (2048ull*2048ull)

__device__ __forceinline__ u16 f2b(float x){
  union { float f; unsigned u; } v; v.f = x;
  unsigned r = v.u + 0x7FFFu + ((v.u >> 16) & 1u);
  return (u16)(r >> 16);
}
__device__ __forceinline__ float b2f(u16 x){
  union { unsigned u; float f; } v; v.u = ((unsigned)x) << 16; return v.f;
}

// ---- fused 3-way mix of A -> A1T, A2T, BT (all transposed bf16 [2][2048][2048])
//      + fused row-sums of A1T (=colsum A1 -> sA1) and BT (=colsum B -> deg2).
//      v2: in-register 4x4 micro-transpose, all-b64 LDS ops, 18.4 KB LDS. ------------
__global__ __launch_bounds__(256)
void k_mix(const float* __restrict__ A,
           const float* __restrict__ w1, const float* __restrict__ w2,
           const float* __restrict__ wl,
           u16* __restrict__ A1T, u16* __restrict__ A2T, u16* __restrict__ BT,
           float* __restrict__ sA1, float* __restrict__ deg2){
  __shared__ u16 lt[2][64][72];
  const int t = threadIdx.x;
  const int mq = t & 15, nr = t >> 4;
  const int n0 = blockIdx.y * 64, m0 = blockIdx.x * 64;
  float f[3][2][5];
  #pragma unroll
  for (int s=0;s<3;s++){
    const float* w = (s==0) ? w1 : (s==1) ? w2 : wl;
    #pragma unroll
    for (int c=0;c<2;c++){
      float m = -1e30f;
      #pragma unroll
      for (int e=0;e<5;e++) m = fmaxf(m, w[e*2+c]);
      float sum = 0.f;
      #pragma unroll
      for (int e=0;e<5;e++){ f[s][c][e] = __expf(w[e*2+c]-m); sum += f[s][c][e]; }
      float inv = 1.f/sum;
      #pragma unroll
      for (int e=0;e<5;e++) f[s][c][e] *= inv;
    }
  }

  // compute all 6 (s,c) 4x4 tiles into registers (n-major: reg[sc][rr], comps = j)
  ushort4 reg[6][4];
  #pragma unroll
  for (int rr=0; rr<4; ++rr){
    const int nl = nr*4 + rr;
    const size_t off = (size_t)(n0+nl)*2048 + m0 + mq*4;
    float4 a0 = *(const float4*)&A[off];
    float4 a1 = *(const float4*)&A[NN + off];
    float4 a2 = *(const float4*)&A[2*NN + off];
    float4 a3 = *(const float4*)&A[3*NN + off];
    float4 a4 = *(const float4*)&A[4*NN + off];
    float ax[4][5] = {{a0.x,a1.x,a2.x,a3.x,a4.x},
                      {a0.y,a1.y,a2.y,a3.y,a4.y},
                      {a0.z,a1.z,a2.z,a3.z,a4.z},
                      {a0.w,a1.w,a2.w,a3.w,a4.w}};
    #pragma unroll
    for (int c=0;c<2;c++){
      #pragma unroll
      for (int j=0;j<4;j++){
        float s1=0.f,s2=0.f,s3=0.f;
        #pragma unroll
        for (int e=0;e<5;e++){
          s1 += ax[j][e]*f[0][c][e];
          s2 += ax[j][e]*f[1][c][e];
          s3 += ax[j][e]*f[2][c][e];
        }
        ((u16*)&reg[0+c][rr])[j] = f2b(s1);
        ((u16*)&reg[2+c][rr])[j] = f2b(s2);
        ((u16*)&reg[4+c][rr])[j] = f2b(s3);
      }
    }
  }

  // per-s: m-major LDS write (in-register transpose), barrier, b64 read + store
  const int nq = t & 15, mr = t >> 4;
  for (int s=0; s<3; ++s){
    if (s) __syncthreads();
    #pragma unroll
    for (int c=0;c<2;c++){
      #pragma unroll
      for (int j=0;j<4;j++){
        ushort4 o;
        o.x = ((const u16*)&reg[s*2+c][0])[j];
        o.y = ((const u16*)&reg[s*2+c][1])[j];
        o.z = ((const u16*)&reg[s*2+c][2])[j];
        o.w = ((const u16*)&reg[s*2+c][3])[j];
        *(ushort4*)&lt[c][mq*4+j][nr*4] = o;
      }
    }
    __syncthreads();
    u16* __restrict__ dst = (s==0) ? A1T : (s==1) ? A2T : BT;
    #pragma unroll
    for (int c=0;c<2;c++){
      #pragma unroll
      for (int rr=0;rr<4;rr++){
        const int ml = mr*4 + rr;
        ushort4 o = *(const ushort4*)&lt[c][ml][nq*4];
        *(ushort4*)&dst[(size_t)c*NN + (size_t)(m0+ml)*2048 + n0 + nq*4] = o;
        if (s != 1){
          float part = b2f(o.x)+b2f(o.y)+b2f(o.z)+b2f(o.w);
          part += __shfl_xor(part, 1); part += __shfl_xor(part, 2);
          part += __shfl_xor(part, 4); part += __shfl_xor(part, 8);
          if (nq == 0){
            float* tgt = (s==0) ? sA1 : deg2;
            atomicAdd(&tgt[c*2048 + m0 + ml], part);
          }
        }
      }
    }
  }
}

// ---- deg1[c][j] = sum_k sA1[c][k] * A2T[c][j][k]  (one wave per row) -----------------
__global__ __launch_bounds__(256)
void k_deg1(const u16* __restrict__ A2T, const float* __restrict__ sA1,
            float* __restrict__ deg1){
  const int g = blockIdx.x*4 + (threadIdx.x >> 6);
  const int lane = threadIdx.x & 63;
  const int c = g >> 11, j = g & 2047;
  const u16* __restrict__ row = A2T + (size_t)c*NN + (size_t)j*2048;
  const float* __restrict__ sv = sA1 + c*2048;
  float s = 0.f;
  #pragma unroll
  for (int it=0; it<4; ++it){
    const int k = it*512 + lane*8;
    us8 v = *(const us8*)&row[k];
    const float4 f0 = *(const float4*)&sv[k];
    const float4 f1 = *(const float4*)&sv[k+4];
    s += b2f(v[0])*f0.x + b2f(v[1])*f0.y + b2f(v[2])*f0.z + b2f(v[3])*f0.w
       + b2f(v[4])*f1.x + b2f(v[5])*f1.y + b2f(v[6])*f1.z + b2f(v[7])*f1.w;
  }
  s += __shfl_xor(s, 1);  s += __shfl_xor(s, 2);  s += __shfl_xor(s, 4);
  s += __shfl_xor(s, 8);  s += __shfl_xor(s, 16); s += __shfl_xor(s, 32);
  if (lane == 0) deg1[c*2048 + j] = s;
}

// ---- weighted column-sum over rows of MT: outv[c][n] += sum_m w[m]*MT[c][m][n] -------
template<int MODE>
__global__ __launch_bounds__(256)
void k_wsum(const u16* __restrict__ MT, const float* __restrict__ va,
            const float* __restrict__ vb, float* __restrict__ outv){
  __shared__ float w[128];
  const int t = threadIdx.x;
  const int n = blockIdx.x * 256 + t;
  const int m0 = blockIdx.y * 128;
  const int c = blockIdx.z;
  if (t < 128){
    const int m = c*2048 + m0 + t;
    float x;
    if (MODE == 0){ float d = va[m]; x = d > 0.f ? 1.f/d : 0.f; }
    else if (MODE == 1){ float d = va[m]; x = (d > 0.f ? 1.f/d : 0.f) * vb[m]; }
    else { x = va[m]; }
    w[t] = x;
  }
  __syncthreads();
  const u16* __restrict__ p = MT + (size_t)c*NN + (size_t)m0*2048 + n;
  float s = 0.f;
  #pragma unroll 4
  for (int m=0;m<128;m++)
    s += b2f(p[(size_t)m*2048]) * w[m];
  atomicAdd(&outv[c*2048 + n], s);
}

// ---------------- hw = h @ gcn_w  (f32), 128 blocks x 16 rows ----------------
__global__ __launch_bounds__(256)
void k_hw(const float* __restrict__ h, const float* __restrict__ W, float* __restrict__ hw){
  __shared__ float lh[16][256];
  int t = threadIdx.x;
  int n0 = blockIdx.x * 16;
  for (int idx = t; idx < 16*256; idx += 256)
    lh[idx >> 8][idx & 255] = h[(size_t)(n0 + (idx>>8))*256 + (idx&255)];
  __syncthreads();
  int d = t & 127, half = t >> 7;
  float acc[8];
  #pragma unroll
  for (int nn=0;nn<8;nn++) acc[nn] = 0.f;
  for (int k=0;k<256;k++){
    float wv = W[(size_t)k*128 + d];
    #pragma unroll
    for (int nn=0;nn<8;nn++) acc[nn] += lh[half*8+nn][k]*wv;
  }
  #pragma unroll
  for (int nn=0;nn<8;nn++) hw[(size_t)(n0 + half*8 + nn)*128 + d] = acc[nn];
}

// ---------------- PT[c][d][n] = bf16(rsqrt(max(rowsum,1)) * hw[n][d]) ----------------
__global__ void k_pt(const float* __restrict__ hw, const float* __restrict__ rowsum,
                     u16* __restrict__ PT){
  int t = threadIdx.x;
  int n = blockIdx.x * 64 + (t & 63);
  int c = blockIdx.y;
  float dv = rsqrtf(fmaxf(rowsum[c*2048 + n], 1.0f));
  for (int d = t >> 6; d < 128; d += 4)
    PT[((size_t)c*128 + d)*2048 + n] = f2b(dv * hw[(size_t)n*128 + d]);
}

// ------- thin bt-GEMM split-K=8 (2-barrier loop), f32 partials: Cp = A @ Bt^T ---------
__global__ __launch_bounds__(256, 2)
void k_gemm3(const u16* __restrict__ A, const u16* __restrict__ Bt, float* __restrict__ Cp){
  __shared__ u16 lA[128*64];
  __shared__ u16 lB[128*64];
  const int tid = threadIdx.x;
  const int bm = blockIdx.x, bk = blockIdx.y, cc = blockIdx.z;
  const u16* __restrict__ Ab = A + (size_t)cc*NN + (size_t)(bm*128)*2048 + bk*256;
  const u16* __restrict__ Bb = Bt + (size_t)cc*(128*2048) + bk*256;
  float* __restrict__ Cb = Cp + ((size_t)bk*2 + cc)*2048*128 + (size_t)(bm*128)*128;
  const int wid = tid >> 6, lane = tid & 63;
  const int wr = wid >> 1, wc = wid & 1;
  const int fl = lane & 15, fk = (lane >> 4) << 3;
  const int srow = (wid << 3) + (lane >> 3);
  const int scol = (lane & 7) << 3;

  f32x4 acc[4][4];
  const f32x4 zero = {0.f,0.f,0.f,0.f};
  #pragma unroll
  for (int i=0;i<4;i++)
    #pragma unroll
    for (int jj=0;jj<4;jj++) acc[i][jj] = zero;

  for (int k0 = 0; k0 < 256; k0 += 64){
    #pragma unroll
    for (int it = 0; it < 4; ++it){
      int r = it*32 + srow;
      __builtin_amdgcn_global_load_lds(
        (const __attribute__((address_space(1))) void*)(Ab + (size_t)r*2048 + k0 + scol),
        (__attribute__((address_space(3))) void*)(&lA[(it*32 + (wid<<3))*64]), 16, 0, 0);
      __builtin_amdgcn_global_load_lds(
        (const __attribute__((address_space(1))) void*)(Bb + (size_t)r*2048 + k0 + scol),
        (__attribute__((address_space(3))) void*)(&lB[(it*32 + (wid<<3))*64]), 16, 0, 0);
    }
    __syncthreads();
    #pragma unroll
    for (int ks = 0; ks < 2; ++ks){
      bf16x8 af[4], bfr[4];
      #pragma unroll
      for (int mi=0;mi<4;mi++)
        af[mi] = *reinterpret_cast<const bf16x8*>(&lA[(wr*64 + mi*16 + fl)*64 + ks*32 + fk]);
      #pragma unroll
      for (int ni=0;ni<4;ni++)
        bfr[ni] = *reinterpret_cast<const bf16x8*>(&lB[(wc*64 + ni*16 + fl)*64 + ks*32 + fk]);
      #pragma unroll
      for (int mi=0;mi<4;mi++)
        #pragma unroll
        for (int ni=0;ni<4;ni++)
          acc[mi][ni] = __builtin_amdgcn_mfma_f32_16x16x32_bf16(af[mi], bfr[ni], acc[mi][ni], 0, 0, 0);
    }
    __syncthreads();
  }
  const int rbase = (lane >> 4) << 2;
  #pragma unroll
  for (int mi=0;mi<4;mi++)
    #pragma unroll
    for (int ni=0;ni<4;ni++)
      #pragma unroll
      for (int r=0;r<4;r++)
        Cb[(size_t)(wr*64 + mi*16 + rbase + r)*128 + wc*64 + ni*16 + fl] = acc[mi][ni][r];
}

// ---- reduce 8 partials (+ optional dinv1 row scale) -> transposed bf16 QT[c][d][m] ---
template<bool SCALE>
__global__ __launch_bounds__(256)
void k_redt(const float* __restrict__ aggp, const float* __restrict__ deg1,
            u16* __restrict__ QT){
  __shared__ u16 lq[128][36];
  const int t = threadIdx.x;
  const int m0 = blockIdx.x * 32, c = blockIdx.y;
  const int d4 = (t & 31) * 4, mr = t >> 5;
  #pragma unroll
  for (int p4=0; p4<4; ++p4){
    const int m = m0 + p4*8 + mr;
    float4 s = {0.f,0.f,0.f,0.f};
    #pragma unroll
    for (int p=0;p<8;p++){
      const float4 v = *(const float4*)&aggp[(((size_t)p*2 + c)*2048 + m)*128 + d4];
      s.x += v.x; s.y += v.y; s.z += v.z; s.w += v.w;
    }
    if (SCALE){
      float dg = deg1[c*2048 + m];
      float di = dg > 0.f ? 1.f/dg : 0.f;
      s.x *= di; s.y *= di; s.z *= di; s.w *= di;
    }
    const int ml = p4*8 + mr;
    lq[d4+0][ml] = f2b(s.x); lq[d4+1][ml] = f2b(s.y);
    lq[d4+2][ml] = f2b(s.z); lq[d4+3][ml] = f2b(s.w);
  }
  __syncthreads();
  const int d = t >> 1, half = t & 1;
  u16* __restrict__ dst = QT + ((size_t)c*128 + d)*2048 + m0 + half*16;
  #pragma unroll
  for (int q=0;q<4;q++){
    ushort4 o;
    o.x = lq[d][half*16 + q*4 + 0];
    o.y = lq[d][half*16 + q*4 + 1];
    o.z = lq[d][half*16 + q*4 + 2];
    o.w = lq[d][half*16 + q*4 + 3];
    *(ushort4*)&dst[q*4] = o;
  }
}

// -------- head: Xc = relu(dinv2[c,m] * sum_p aggp + gb); out = relu(Xc@W1+b1)@W2+b2 ---
__global__ __launch_bounds__(256)
void k_head(const float* __restrict__ aggp, const float* __restrict__ deg2,
            const float* __restrict__ gb,
            const float* __restrict__ W1, const float* __restrict__ b1,
            const float* __restrict__ W2, const float* __restrict__ b2,
            float* __restrict__ out){
  __shared__ float lx[16][256];
  __shared__ float lt[16][132];
  int t = threadIdx.x;
  int n0 = blockIdx.x * 16;
  for (int idx = t; idx < 1024; idx += 256){
    int row = idx >> 6;
    int q = idx & 63;
    int c = q >> 5, d4 = (q & 31) * 4;
    float dg = deg2[c*2048 + n0 + row];
    float di = dg > 0.f ? 1.f/dg : 0.f;
    float4 s = {0.f,0.f,0.f,0.f};
    #pragma unroll
    for (int p=0;p<8;p++){
      const float4 v = *(const float4*)&aggp[(((size_t)p*2 + c)*2048 + n0 + row)*128 + d4];
      s.x += v.x; s.y += v.y; s.z += v.z; s.w += v.w;
    }
    const float4 bv = *(const float4*)&gb[d4];
    s.x = fmaxf(s.x*di + bv.x, 0.f); s.y = fmaxf(s.y*di + bv.y, 0.f);
    s.z = fmaxf(s.z*di + bv.z, 0.f); s.w = fmaxf(s.w*di + bv.w, 0.f);
    *(float4*)&lx[row][c*128 + d4] = s;
  }
  __syncthreads();
  int d = t & 127, half = t >> 7;
  float acc[8];
  #pragma unroll
  for (int nn=0;nn<8;nn++) acc[nn] = 0.f;
  for (int k=0;k<256;k++){
    float wv = W1[(size_t)k*128 + d];
    #pragma unroll
    for (int nn=0;nn<8;nn++) acc[nn] += lx[half*8+nn][k]*wv;
  }
  float bb = b1[d];
  #pragma unroll
  for (int nn=0;nn<8;nn++){
    float v = acc[nn] + bb;
    lt[half*8+nn][d] = v > 0.f ? v : 0.f;
  }
  __syncthreads();
  {
    int row = t >> 4, q = t & 15;
    float s = b2[q];
    for (int dd=0; dd<128; dd++) s += lt[row][dd] * W2[(size_t)dd*16 + q];
    out[(size_t)(n0+row)*16 + q] = s;
  }
}

extern "C" void kernel_launch(void* const* d_in, const int* in_sizes, int n_in,
                              void* d_out, int out_size, void* d_ws, size_t ws_size,
                              hipStream_t stream){
  const float* A   = (const float*)d_in[0];
  const float* h   = (const float*)d_in[1];
  const float* w1  = (const float*)d_in[2];
  const float* w2  = (const float*)d_in[3];
  const float* wl  = (const float*)d_in[4];
  const float* gw  = (const float*)d_in[5];
  const float* gb  = (const float*)d_in[6];
  const float* l1w = (const float*)d_in[7];
  const float* l1b = (const float*)d_in[8];
  const float* l2w = (const float*)d_in[9];
  const float* l2b = (const float*)d_in[10];
  float* out = (float*)d_out;
  char* ws = (char*)d_ws;

  const size_t SZ = 2*NN*2;     // 16.78 MB (one bf16 [2][2048][2048])
  u16*  A1T  = (u16*)(ws);
  u16*  A2T  = (u16*)(ws + 1*SZ);
  u16*  BT   = (u16*)(ws + 2*SZ);
  float* aggp= (float*)(ws + 3*SZ);               // 8 x 2 x 2048 x 128 f32 = 16.78MB
  char* tail = ws + 4*SZ;
  float* hw    = (float*)tail;                    // 1MB
  u16*  PT     = (u16*)(tail + 1048576);          // 1MB
  u16*  Q1T    = (u16*)(tail + 2*1048576);        // 1MB
  u16*  Q2T    = (u16*)(tail + 3*1048576);        // 1MB
  float* sA1   = (float*)(tail + 4*1048576);      // 6 vectors x 2ch x 2048 f32
  float* deg1  = sA1 + 4096;
  float* deg2  = deg1 + 4096;
  float* v1    = deg2 + 4096;
  float* v3    = v1 + 4096;
  float* rowsum= v3 + 4096;

  const size_t TOTAL = 4*SZ + 4*1048576 + 6*4096*4;
  if (ws_size < TOTAL){ hipMemsetAsync(d_out, 0, (size_t)out_size*4, stream); return; }

  // zero atomics targets: sA1, deg1(harmless), deg2, v1, v3, rowsum
  hipMemsetAsync(sA1, 0, 6*4096*4, stream);

  // A -> A1T, A2T, BT + sA1 (colsum A1), deg2 (colsum B)
  k_mix<<<dim3(32,32), 256, 0, stream>>>(A, w1, w2, wl, A1T, A2T, BT, sA1, deg2);
  // deg1 = sA1 @ A2 (row-dot over A2T)
  k_deg1<<<1024, 256, 0, stream>>>(A2T, sA1, deg1);
  // rowsum chain: v1 = B@dinv2 ; v3 = A2@(dinv1*v1) ; rowsum = A1@v3
  k_wsum<0><<<dim3(8,16,2), 256, 0, stream>>>(BT, deg2, deg2, v1);
  k_wsum<1><<<dim3(8,16,2), 256, 0, stream>>>(A2T, deg1, v1, v3);
  k_wsum<2><<<dim3(8,16,2), 256, 0, stream>>>(A1T, v3, v3, rowsum);
  // features
  k_hw<<<128, 256, 0, stream>>>(h, gw, hw);
  k_pt<<<dim3(32,2), 256, 0, stream>>>(hw, rowsum, PT);
  // agg chain: Q1 = A1^T@P ; Q2 = dinv1*(A2^T@Q1) ; Q3 = B^T@Q2 ; (dinv2 in head)
  k_gemm3<<<dim3(16,8,2), 256, 0, stream>>>(A1T, PT, aggp);
  k_redt<false><<<dim3(64,2), 256, 0, stream>>>(aggp, deg1, Q1T);
  k_gemm3<<<dim3(16,8,2), 256, 0, stream>>>(A2T, Q1T, aggp);
  k_redt<true><<<dim3(64,2), 256, 0, stream>>>(aggp, deg1, Q2T);
  k_gemm3<<<dim3(16,8,2), 256, 0, stream>>>(BT, Q2T, aggp);
  k_head<<<128, 256, 0, stream>>>(aggp, deg2, gb, l1w, l1b, l2w, l2b, out);
}

// Round 10
// 159.993 us; speedup vs baseline: 1.2416x; 1.0259x over previous
//
#include <hip/hip_runtime.h>

typedef unsigned short u16;
typedef __attribute__((ext_vector_type(4))) float f32x4;
typedef __attribute__((ext_vector_type(8))) __bf16 bf16x8;
typedef __attribute__((ext_vector_type(8))) unsigned short us8;

#define NN (2048ull*2048ull)

__device__ __forceinline__ u16 f2b(float x){
  union { float f; unsigned u; } v; v.f = x;
  unsigned r = v.u + 0x7FFFu + ((v.u >> 16) & 1u);
  return (u16)(r >> 16);
}
__device__ __forceinline__ float b2f(u16 x){
  union { unsigned u; float f; } v; v.u = ((unsigned)x) << 16; return v.f;
}

// ---- fused 3-way mix of A -> A1T, A2T, BT (all transposed bf16 [2][2048][2048])
//      + fused row-sums of A1T (=colsum A1 -> sA1) and BT (=colsum B -> deg2).
//      v3: [64][68] padding (write conflicts 8-way -> 4-way). -------------------------
__global__ __launch_bounds__(256)
void k_mix(const float* __restrict__ A,
           const float* __restrict__ w1, const float* __restrict__ w2,
           const float* __restrict__ wl,
           u16* __restrict__ A1T, u16* __restrict__ A2T, u16* __restrict__ BT,
           float* __restrict__ sA1, float* __restrict__ deg2){
  __shared__ u16 lt[2][64][68];
  const int t = threadIdx.x;
  const int mq = t & 15, nr = t >> 4;
  const int n0 = blockIdx.y * 64, m0 = blockIdx.x * 64;
  float f[3][2][5];
  #pragma unroll
  for (int s=0;s<3;s++){
    const float* w = (s==0) ? w1 : (s==1) ? w2 : wl;
    #pragma unroll
    for (int c=0;c<2;c++){
      float m = -1e30f;
      #pragma unroll
      for (int e=0;e<5;e++) m = fmaxf(m, w[e*2+c]);
      float sum = 0.f;
      #pragma unroll
      for (int e=0;e<5;e++){ f[s][c][e] = __expf(w[e*2+c]-m); sum += f[s][c][e]; }
      float inv = 1.f/sum;
      #pragma unroll
      for (int e=0;e<5;e++) f[s][c][e] *= inv;
    }
  }

  // compute all 6 (s,c) 4x4 tiles into registers (n-major: reg[sc][rr], comps = j)
  ushort4 reg[6][4];
  #pragma unroll
  for (int rr=0; rr<4; ++rr){
    const int nl = nr*4 + rr;
    const size_t off = (size_t)(n0+nl)*2048 + m0 + mq*4;
    float4 a0 = *(const float4*)&A[off];
    float4 a1 = *(const float4*)&A[NN + off];
    float4 a2 = *(const float4*)&A[2*NN + off];
    float4 a3 = *(const float4*)&A[3*NN + off];
    float4 a4 = *(const float4*)&A[4*NN + off];
    float ax[4][5] = {{a0.x,a1.x,a2.x,a3.x,a4.x},
                      {a0.y,a1.y,a2.y,a3.y,a4.y},
                      {a0.z,a1.z,a2.z,a3.z,a4.z},
                      {a0.w,a1.w,a2.w,a3.w,a4.w}};
    #pragma unroll
    for (int c=0;c<2;c++){
      #pragma unroll
      for (int j=0;j<4;j++){
        float s1=0.f,s2=0.f,s3=0.f;
        #pragma unroll
        for (int e=0;e<5;e++){
          s1 += ax[j][e]*f[0][c][e];
          s2 += ax[j][e]*f[1][c][e];
          s3 += ax[j][e]*f[2][c][e];
        }
        ((u16*)&reg[0+c][rr])[j] = f2b(s1);
        ((u16*)&reg[2+c][rr])[j] = f2b(s2);
        ((u16*)&reg[4+c][rr])[j] = f2b(s3);
      }
    }
  }

  // per-s: m-major LDS write (in-register transpose), barrier, b64 read + store
  const int nq = t & 15, mr = t >> 4;
  for (int s=0; s<3; ++s){
    if (s) __syncthreads();
    #pragma unroll
    for (int c=0;c<2;c++){
      #pragma unroll
      for (int j=0;j<4;j++){
        ushort4 o;
        o.x = ((const u16*)&reg[s*2+c][0])[j];
        o.y = ((const u16*)&reg[s*2+c][1])[j];
        o.z = ((const u16*)&reg[s*2+c][2])[j];
        o.w = ((const u16*)&reg[s*2+c][3])[j];
        *(ushort4*)&lt[c][mq*4+j][nr*4] = o;
      }
    }
    __syncthreads();
    u16* __restrict__ dst = (s==0) ? A1T : (s==1) ? A2T : BT;
    #pragma unroll
    for (int c=0;c<2;c++){
      #pragma unroll
      for (int rr=0;rr<4;rr++){
        const int ml = mr*4 + rr;
        ushort4 o = *(const ushort4*)&lt[c][ml][nq*4];
        *(ushort4*)&dst[(size_t)c*NN + (size_t)(m0+ml)*2048 + n0 + nq*4] = o;
        if (s != 1){
          float part = b2f(o.x)+b2f(o.y)+b2f(o.z)+b2f(o.w);
          part += __shfl_xor(part, 1); part += __shfl_xor(part, 2);
          part += __shfl_xor(part, 4); part += __shfl_xor(part, 8);
          if (nq == 0){
            float* tgt = (s==0) ? sA1 : deg2;
            atomicAdd(&tgt[c*2048 + m0 + ml], part);
          }
        }
      }
    }
  }
}

// ---- deg1[c][j] = sum_k sA1[c][k] * A2T[c][j][k]  (one wave per row) -----------------
__global__ __launch_bounds__(256)
void k_deg1(const u16* __restrict__ A2T, const float* __restrict__ sA1,
            float* __restrict__ deg1){
  const int g = blockIdx.x*4 + (threadIdx.x >> 6);
  const int lane = threadIdx.x & 63;
  const int c = g >> 11, j = g & 2047;
  const u16* __restrict__ row = A2T + (size_t)c*NN + (size_t)j*2048;
  const float* __restrict__ sv = sA1 + c*2048;
  float s = 0.f;
  #pragma unroll
  for (int it=0; it<4; ++it){
    const int k = it*512 + lane*8;
    us8 v = *(const us8*)&row[k];
    const float4 f0 = *(const float4*)&sv[k];
    const float4 f1 = *(const float4*)&sv[k+4];
    s += b2f(v[0])*f0.x + b2f(v[1])*f0.y + b2f(v[2])*f0.z + b2f(v[3])*f0.w
       + b2f(v[4])*f1.x + b2f(v[5])*f1.y + b2f(v[6])*f1.z + b2f(v[7])*f1.w;
  }
  s += __shfl_xor(s, 1);  s += __shfl_xor(s, 2);  s += __shfl_xor(s, 4);
  s += __shfl_xor(s, 8);  s += __shfl_xor(s, 16); s += __shfl_xor(s, 32);
  if (lane == 0) deg1[c*2048 + j] = s;
}

// ---- weighted column-sum over rows of MT: outv[c][n] += sum_m w[m]*MT[c][m][n] -------
// 64-row strips (1024 blocks)
template<int MODE>
__global__ __launch_bounds__(256)
void k_wsum(const u16* __restrict__ MT, const float* __restrict__ va,
            const float* __restrict__ vb, float* __restrict__ outv){
  __shared__ float w[64];
  const int t = threadIdx.x;
  const int n = blockIdx.x * 256 + t;
  const int m0 = blockIdx.y * 64;
  const int c = blockIdx.z;
  if (t < 64){
    const int m = c*2048 + m0 + t;
    float x;
    if (MODE == 0){ float d = va[m]; x = d > 0.f ? 1.f/d : 0.f; }
    else if (MODE == 1){ float d = va[m]; x = (d > 0.f ? 1.f/d : 0.f) * vb[m]; }
    else { x = va[m]; }
    w[t] = x;
  }
  __syncthreads();
  const u16* __restrict__ p = MT + (size_t)c*NN + (size_t)m0*2048 + n;
  float s = 0.f;
  #pragma unroll 4
  for (int m=0;m<64;m++)
    s += b2f(p[(size_t)m*2048]) * w[m];
  atomicAdd(&outv[c*2048 + n], s);
}

// ---- fused hw = h@gcn_w then PT[c][d][n] = bf16(rsqrt(max(rowsum,1))*hw[n][d]) ------
// 256 blocks x 8 rows
__global__ __launch_bounds__(256)
void k_hwpt(const float* __restrict__ h, const float* __restrict__ W,
            const float* __restrict__ rowsum, u16* __restrict__ PT){
  __shared__ float lh[8][256];
  int t = threadIdx.x;
  int n0 = blockIdx.x * 8;
  for (int idx = t; idx < 8*256; idx += 256)
    lh[idx >> 8][idx & 255] = h[(size_t)(n0 + (idx>>8))*256 + (idx&255)];
  __syncthreads();
  int d = t & 127, half = t >> 7;
  float acc[4];
  #pragma unroll
  for (int nn=0;nn<4;nn++) acc[nn] = 0.f;
  for (int k=0;k<256;k++){
    float wv = W[(size_t)k*128 + d];
    #pragma unroll
    for (int nn=0;nn<4;nn++) acc[nn] += lh[half*4+nn][k]*wv;
  }
  #pragma unroll
  for (int c=0;c<2;c++){
    ushort4 o;
    #pragma unroll
    for (int nn=0;nn<4;nn++){
      int n = n0 + half*4 + nn;
      float dv = rsqrtf(fmaxf(rowsum[c*2048 + n], 1.0f));
      ((u16*)&o)[nn] = f2b(dv * acc[nn]);
    }
    *(ushort4*)&PT[((size_t)c*128 + d)*2048 + n0 + half*4] = o;
  }
}

// ------- thin bt-GEMM split-K=8 (2-barrier loop), atomic f32 C: Agg += A @ Bt^T ------
__global__ __launch_bounds__(256, 2)
void k_gemm3(const u16* __restrict__ A, const u16* __restrict__ Bt, float* __restrict__ Agg){
  __shared__ u16 lA[128*64];
  __shared__ u16 lB[128*64];
  const int tid = threadIdx.x;
  const int bm = blockIdx.x, bk = blockIdx.y, cc = blockIdx.z;
  const u16* __restrict__ Ab = A + (size_t)cc*NN + (size_t)(bm*128)*2048 + bk*256;
  const u16* __restrict__ Bb = Bt + (size_t)cc*(128*2048) + bk*256;
  float* __restrict__ Cb = Agg + (size_t)cc*2048*128 + (size_t)(bm*128)*128;
  const int wid = tid >> 6, lane = tid & 63;
  const int wr = wid >> 1, wc = wid & 1;
  const int fl = lane & 15, fk = (lane >> 4) << 3;
  const int srow = (wid << 3) + (lane >> 3);
  const int scol = (lane & 7) << 3;

  f32x4 acc[4][4];
  const f32x4 zero = {0.f,0.f,0.f,0.f};
  #pragma unroll
  for (int i=0;i<4;i++)
    #pragma unroll
    for (int jj=0;jj<4;jj++) acc[i][jj] = zero;

  for (int k0 = 0; k0 < 256; k0 += 64){
    #pragma unroll
    for (int it = 0; it < 4; ++it){
      int r = it*32 + srow;
      __builtin_amdgcn_global_load_lds(
        (const __attribute__((address_space(1))) void*)(Ab + (size_t)r*2048 + k0 + scol),
        (__attribute__((address_space(3))) void*)(&lA[(it*32 + (wid<<3))*64]), 16, 0, 0);
      __builtin_amdgcn_global_load_lds(
        (const __attribute__((address_space(1))) void*)(Bb + (size_t)r*2048 + k0 + scol),
        (__attribute__((address_space(3))) void*)(&lB[(it*32 + (wid<<3))*64]), 16, 0, 0);
    }
    __syncthreads();
    #pragma unroll
    for (int ks = 0; ks < 2; ++ks){
      bf16x8 af[4], bfr[4];
      #pragma unroll
      for (int mi=0;mi<4;mi++)
        af[mi] = *reinterpret_cast<const bf16x8*>(&lA[(wr*64 + mi*16 + fl)*64 + ks*32 + fk]);
      #pragma unroll
      for (int ni=0;ni<4;ni++)
        bfr[ni] = *reinterpret_cast<const bf16x8*>(&lB[(wc*64 + ni*16 + fl)*64 + ks*32 + fk]);
      #pragma unroll
      for (int mi=0;mi<4;mi++)
        #pragma unroll
        for (int ni=0;ni<4;ni++)
          acc[mi][ni] = __builtin_amdgcn_mfma_f32_16x16x32_bf16(af[mi], bfr[ni], acc[mi][ni], 0, 0, 0);
    }
    __syncthreads();
  }
  const int rbase = (lane >> 4) << 2;
  #pragma unroll
  for (int mi=0;mi<4;mi++)
    #pragma unroll
    for (int ni=0;ni<4;ni++)
      #pragma unroll
      for (int r=0;r<4;r++)
        atomicAdd(&Cb[(size_t)(wr*64 + mi*16 + rbase + r)*128 + wc*64 + ni*16 + fl],
                  acc[mi][ni][r]);
}

// ---- Agg f32 [c][2048][128] (+ optional dinv1 row scale) -> transposed bf16 QT ------
template<bool SCALE>
__global__ __launch_bounds__(256)
void k_qt(const float* __restrict__ Agg, const float* __restrict__ deg1,
          u16* __restrict__ QT){
  __shared__ u16 lq[128][36];
  const int t = threadIdx.x;
  const int m0 = blockIdx.x * 32, c = blockIdx.y;
  const int d4 = (t & 31) * 4, mr = t >> 5;
  #pragma unroll
  for (int p4=0; p4<4; ++p4){
    const int m = m0 + p4*8 + mr;
    float4 s = *(const float4*)&Agg[((size_t)c*2048 + m)*128 + d4];
    if (SCALE){
      float dg = deg1[c*2048 + m];
      float di = dg > 0.f ? 1.f/dg : 0.f;
      s.x *= di; s.y *= di; s.z *= di; s.w *= di;
    }
    const int ml = p4*8 + mr;
    lq[d4+0][ml] = f2b(s.x); lq[d4+1][ml] = f2b(s.y);
    lq[d4+2][ml] = f2b(s.z); lq[d4+3][ml] = f2b(s.w);
  }
  __syncthreads();
  const int d = t >> 1, half = t & 1;
  u16* __restrict__ dst = QT + ((size_t)c*128 + d)*2048 + m0 + half*16;
  #pragma unroll
  for (int q=0;q<4;q++){
    ushort4 o;
    o.x = lq[d][half*16 + q*4 + 0];
    o.y = lq[d][half*16 + q*4 + 1];
    o.z = lq[d][half*16 + q*4 + 2];
    o.w = lq[d][half*16 + q*4 + 3];
    *(ushort4*)&dst[q*4] = o;
  }
}

// -------- head: Xc = relu(dinv2[c,m]*agg3 + gb); out = relu(Xc@W1+b1)@W2+b2 ----------
// 256 blocks x 8 rows
__global__ __launch_bounds__(256)
void k_head(const float* __restrict__ agg3, const float* __restrict__ deg2,
            const float* __restrict__ gb,
            const float* __restrict__ W1, const float* __restrict__ b1,
            const float* __restrict__ W2, const float* __restrict__ b2,
            float* __restrict__ out){
  __shared__ float lx[8][256];
  __shared__ float lt[8][132];
  int t = threadIdx.x;
  int n0 = blockIdx.x * 8;
  for (int idx = t; idx < 512; idx += 256){
    int row = idx >> 6;
    int q = idx & 63;
    int c = q >> 5, d4 = (q & 31) * 4;
    float dg = deg2[c*2048 + n0 + row];
    float di = dg > 0.f ? 1.f/dg : 0.f;
    float4 s = *(const float4*)&agg3[((size_t)c*2048 + n0 + row)*128 + d4];
    const float4 bv = *(const float4*)&gb[d4];
    s.x = fmaxf(s.x*di + bv.x, 0.f); s.y = fmaxf(s.y*di + bv.y, 0.f);
    s.z = fmaxf(s.z*di + bv.z, 0.f); s.w = fmaxf(s.w*di + bv.w, 0.f);
    *(float4*)&lx[row][c*128 + d4] = s;
  }
  __syncthreads();
  int d = t & 127, half = t >> 7;
  float acc[4];
  #pragma unroll
  for (int nn=0;nn<4;nn++) acc[nn] = 0.f;
  for (int k=0;k<256;k++){
    float wv = W1[(size_t)k*128 + d];
    #pragma unroll
    for (int nn=0;nn<4;nn++) acc[nn] += lx[half*4+nn][k]*wv;
  }
  float bb = b1[d];
  #pragma unroll
  for (int nn=0;nn<4;nn++){
    float v = acc[nn] + bb;
    lt[half*4+nn][d] = v > 0.f ? v : 0.f;
  }
  __syncthreads();
  if (t < 128){
    int row = t >> 4, q = t & 15;
    float s = b2[q];
    for (int dd=0; dd<128; dd++) s += lt[row][dd] * W2[(size_t)dd*16 + q];
    out[(size_t)(n0+row)*16 + q] = s;
  }
}

extern "C" void kernel_launch(void* const* d_in, const int* in_sizes, int n_in,
                              void* d_out, int out_size, void* d_ws, size_t ws_size,
                              hipStream_t stream){
  const float* A   = (const float*)d_in[0];
  const float* h   = (const float*)d_in[1];
  const float* w1  = (const float*)d_in[2];
  const float* w2  = (const float*)d_in[3];
  const float* wl  = (const float*)d_in[4];
  const float* gw  = (const float*)d_in[5];
  const float* gb  = (const float*)d_in[6];
  const float* l1w = (const float*)d_in[7];
  const float* l1b = (const float*)d_in[8];
  const float* l2w = (const float*)d_in[9];
  const float* l2b = (const float*)d_in[10];
  float* out = (float*)d_out;
  char* ws = (char*)d_ws;

  const size_t SZ = 2*NN*2;     // 16.78 MB (one bf16 [2][2048][2048])
  const size_t AGG = (size_t)2*2048*128*4;   // 2 MB
  u16*  A1T  = (u16*)(ws);
  u16*  A2T  = (u16*)(ws + 1*SZ);
  u16*  BT   = (u16*)(ws + 2*SZ);
  char* tail = ws + 3*SZ;
  u16*  PT     = (u16*)tail;                      // 1MB
  u16*  Q1T    = (u16*)(tail + 1048576);          // 1MB
  u16*  Q2T    = (u16*)(tail + 2*1048576);        // 1MB
  float* sA1   = (float*)(tail + 3*1048576);      // zeroed region starts here
  float* deg1  = sA1 + 4096;
  float* deg2  = deg1 + 4096;
  float* v1    = deg2 + 4096;
  float* v3    = v1 + 4096;
  float* rowsum= v3 + 4096;
  float* agg1  = rowsum + 4096;                   // 3 x 2MB
  float* agg2  = agg1 + 2*2048*128;
  float* agg3  = agg2 + 2*2048*128;
  const size_t ZBYTES = 6*4096*4 + 3*AGG;

  const size_t TOTAL = 3*SZ + 3*1048576 + ZBYTES;
  if (ws_size < TOTAL){ hipMemsetAsync(d_out, 0, (size_t)out_size*4, stream); return; }

  hipMemsetAsync(sA1, 0, ZBYTES, stream);

  // A -> A1T, A2T, BT + sA1 (colsum A1), deg2 (colsum B)
  k_mix<<<dim3(32,32), 256, 0, stream>>>(A, w1, w2, wl, A1T, A2T, BT, sA1, deg2);
  // deg1 = sA1 @ A2 (row-dot over A2T)
  k_deg1<<<1024, 256, 0, stream>>>(A2T, sA1, deg1);
  // rowsum chain: v1 = B@dinv2 ; v3 = A2@(dinv1*v1) ; rowsum = A1@v3
  k_wsum<0><<<dim3(8,32,2), 256, 0, stream>>>(BT, deg2, deg2, v1);
  k_wsum<1><<<dim3(8,32,2), 256, 0, stream>>>(A2T, deg1, v1, v3);
  k_wsum<2><<<dim3(8,32,2), 256, 0, stream>>>(A1T, v3, v3, rowsum);
  // features: PT = dout * (h@gcn_w)^T
  k_hwpt<<<256, 256, 0, stream>>>(h, gw, rowsum, PT);
  // agg chain: Q1 = A1^T@P ; Q2 = dinv1*(A2^T@Q1) ; agg3 = B^T@Q2 ; (dinv2 in head)
  k_gemm3<<<dim3(16,8,2), 256, 0, stream>>>(A1T, PT, agg1);
  k_qt<false><<<dim3(64,2), 256, 0, stream>>>(agg1, deg1, Q1T);
  k_gemm3<<<dim3(16,8,2), 256, 0, stream>>>(A2T, Q1T, agg2);
  k_qt<true><<<dim3(64,2), 256, 0, stream>>>(agg2, deg1, Q2T);
  k_gemm3<<<dim3(16,8,2), 256, 0, stream>>>(BT, Q2T, agg3);
  k_head<<<256, 256, 0, stream>>>(agg3, deg2, gb, l1w, l1b, l2w, l2b, out);
}

// Round 11
// 156.697 us; speedup vs baseline: 1.2677x; 1.0210x over previous
//
#include <hip/hip_runtime.h>

typedef unsigned short u16;
typedef __attribute__((ext_vector_type(4))) float f32x4;
typedef __attribute__((ext_vector_type(8))) __bf16 bf16x8;
typedef __attribute__((ext_vector_type(8))) unsigned short us8;

#define NN (2048ull*2048ull)

__device__ __forceinline__ u16 f2b(float x){
  union { float f; unsigned u; } v; v.f = x;
  unsigned r = v.u + 0x7FFFu + ((v.u >> 16) & 1u);
  return (u16)(r >> 16);
}
__device__ __forceinline__ float b2f(u16 x){
  union { unsigned u; float f; } v; v.u = ((unsigned)x) << 16; return v.f;
}

// ---- fused 3-way mix of A -> A1T, A2T, BT (all transposed bf16 [2][2048][2048])
//      + fused row-sums of A1T (=colsum A1 -> sA1) and BT (=colsum B -> deg2).
//      v5: 4 LDS buffers, 3 barriers (was 6) -- latency-bound fix. -------------------
__global__ __launch_bounds__(256)
void k_mix(const float* __restrict__ A,
           const float* __restrict__ w1, const float* __restrict__ w2,
           const float* __restrict__ wl,
           u16* __restrict__ A1T, u16* __restrict__ A2T, u16* __restrict__ BT,
           float* __restrict__ sA1, float* __restrict__ deg2){
  __shared__ u16 lt[4][64][68];
  const int t = threadIdx.x;
  const int mq = t & 15, nr = t >> 4;
  const int n0 = blockIdx.y * 64, m0 = blockIdx.x * 64;
  float f[3][2][5];
  #pragma unroll
  for (int s=0;s<3;s++){
    const float* w = (s==0) ? w1 : (s==1) ? w2 : wl;
    #pragma unroll
    for (int c=0;c<2;c++){
      float m = -1e30f;
      #pragma unroll
      for (int e=0;e<5;e++) m = fmaxf(m, w[e*2+c]);
      float sum = 0.f;
      #pragma unroll
      for (int e=0;e<5;e++){ f[s][c][e] = __expf(w[e*2+c]-m); sum += f[s][c][e]; }
      float inv = 1.f/sum;
      #pragma unroll
      for (int e=0;e<5;e++) f[s][c][e] *= inv;
    }
  }

  // compute all 6 (s,c) 4x4 tiles into registers (n-major: reg[sc][rr], comps = j)
  ushort4 reg[6][4];
  #pragma unroll
  for (int rr=0; rr<4; ++rr){
    const int nl = nr*4 + rr;
    const size_t off = (size_t)(n0+nl)*2048 + m0 + mq*4;
    float4 a0 = *(const float4*)&A[off];
    float4 a1 = *(const float4*)&A[NN + off];
    float4 a2 = *(const float4*)&A[2*NN + off];
    float4 a3 = *(const float4*)&A[3*NN + off];
    float4 a4 = *(const float4*)&A[4*NN + off];
    float ax[4][5] = {{a0.x,a1.x,a2.x,a3.x,a4.x},
                      {a0.y,a1.y,a2.y,a3.y,a4.y},
                      {a0.z,a1.z,a2.z,a3.z,a4.z},
                      {a0.w,a1.w,a2.w,a3.w,a4.w}};
    #pragma unroll
    for (int c=0;c<2;c++){
      #pragma unroll
      for (int j=0;j<4;j++){
        float s1=0.f,s2=0.f,s3=0.f;
        #pragma unroll
        for (int e=0;e<5;e++){
          s1 += ax[j][e]*f[0][c][e];
          s2 += ax[j][e]*f[1][c][e];
          s3 += ax[j][e]*f[2][c][e];
        }
        ((u16*)&reg[0+c][rr])[j] = f2b(s1);
        ((u16*)&reg[2+c][rr])[j] = f2b(s2);
        ((u16*)&reg[4+c][rr])[j] = f2b(s3);
      }
    }
  }

  const int nq = t & 15, mr = t >> 4;

  // phase B1: write s=0 (A1T) and s=1 (A2T), both channels, into buffers 0..3
  #pragma unroll
  for (int sc=0; sc<4; ++sc){
    #pragma unroll
    for (int j=0;j<4;j++){
      ushort4 o;
      o.x = ((const u16*)&reg[sc][0])[j];
      o.y = ((const u16*)&reg[sc][1])[j];
      o.z = ((const u16*)&reg[sc][2])[j];
      o.w = ((const u16*)&reg[sc][3])[j];
      *(ushort4*)&lt[sc][mq*4+j][nr*4] = o;
    }
  }
  __syncthreads();
  // phase C1: read/store A1T (+sA1 reduce) and A2T
  #pragma unroll
  for (int sc=0; sc<4; ++sc){
    u16* __restrict__ dst = (sc<2) ? A1T : A2T;
    const int c = sc & 1;
    #pragma unroll
    for (int rr=0;rr<4;rr++){
      const int ml = mr*4 + rr;
      ushort4 o = *(const ushort4*)&lt[sc][ml][nq*4];
      *(ushort4*)&dst[(size_t)c*NN + (size_t)(m0+ml)*2048 + n0 + nq*4] = o;
      if (sc < 2){
        float part = b2f(o.x)+b2f(o.y)+b2f(o.z)+b2f(o.w);
        part += __shfl_xor(part, 1); part += __shfl_xor(part, 2);
        part += __shfl_xor(part, 4); part += __shfl_xor(part, 8);
        if (nq == 0) atomicAdd(&sA1[c*2048 + m0 + ml], part);
      }
    }
  }
  __syncthreads();
  // phase B2: write s=2 (BT) into buffers 0,1
  #pragma unroll
  for (int c=0;c<2;c++){
    #pragma unroll
    for (int j=0;j<4;j++){
      ushort4 o;
      o.x = ((const u16*)&reg[4+c][0])[j];
      o.y = ((const u16*)&reg[4+c][1])[j];
      o.z = ((const u16*)&reg[4+c][2])[j];
      o.w = ((const u16*)&reg[4+c][3])[j];
      *(ushort4*)&lt[c][mq*4+j][nr*4] = o;
    }
  }
  __syncthreads();
  // phase C2: read/store BT (+deg2 reduce)
  #pragma unroll
  for (int c=0;c<2;c++){
    #pragma unroll
    for (int rr=0;rr<4;rr++){
      const int ml = mr*4 + rr;
      ushort4 o = *(const ushort4*)&lt[c][ml][nq*4];
      *(ushort4*)&BT[(size_t)c*NN + (size_t)(m0+ml)*2048 + n0 + nq*4] = o;
      float part = b2f(o.x)+b2f(o.y)+b2f(o.z)+b2f(o.w);
      part += __shfl_xor(part, 1); part += __shfl_xor(part, 2);
      part += __shfl_xor(part, 4); part += __shfl_xor(part, 8);
      if (nq == 0) atomicAdd(&deg2[c*2048 + m0 + ml], part);
    }
  }
}

// ---- merged: blocks 0..1023 -> deg1[c][j] = sum_k sA1[c][k]*A2T[c][j][k]
//              blocks 1024..1535 -> v1[c][n] += sum_m BT[c][m][n]*inv(deg2[c][m]) -----
__global__ __launch_bounds__(256)
void k_post1(const u16* __restrict__ A2T, const u16* __restrict__ BT,
             const float* __restrict__ sA1, const float* __restrict__ deg2,
             float* __restrict__ deg1, float* __restrict__ v1){
  const int b = blockIdx.x;
  const int t = threadIdx.x;
  if (b < 1024){
    const int g = b*4 + (t >> 6);
    const int lane = t & 63;
    const int c = g >> 11, j = g & 2047;
    const u16* __restrict__ row = A2T + (size_t)c*NN + (size_t)j*2048;
    const float* __restrict__ sv = sA1 + c*2048;
    float s = 0.f;
    #pragma unroll
    for (int it=0; it<4; ++it){
      const int k = it*512 + lane*8;
      us8 v = *(const us8*)&row[k];
      const float4 f0 = *(const float4*)&sv[k];
      const float4 f1 = *(const float4*)&sv[k+4];
      s += b2f(v[0])*f0.x + b2f(v[1])*f0.y + b2f(v[2])*f0.z + b2f(v[3])*f0.w
         + b2f(v[4])*f1.x + b2f(v[5])*f1.y + b2f(v[6])*f1.z + b2f(v[7])*f1.w;
    }
    s += __shfl_xor(s, 1);  s += __shfl_xor(s, 2);  s += __shfl_xor(s, 4);
    s += __shfl_xor(s, 8);  s += __shfl_xor(s, 16); s += __shfl_xor(s, 32);
    if (lane == 0) deg1[c*2048 + j] = s;
  } else {
    __shared__ float w[64];
    const int bx = b - 1024;
    const int x = bx & 7, y = (bx >> 3) & 31, c = bx >> 8;
    const int n = x * 256 + t;
    const int m0 = y * 64;
    if (t < 64){
      float d = deg2[c*2048 + m0 + t];
      w[t] = d > 0.f ? 1.f/d : 0.f;
    }
    __syncthreads();
    const u16* __restrict__ p = BT + (size_t)c*NN + (size_t)m0*2048 + n;
    float s = 0.f;
    #pragma unroll 4
    for (int m=0;m<64;m++)
      s += b2f(p[(size_t)m*2048]) * w[m];
    atomicAdd(&v1[c*2048 + n], s);
  }
}

// ---- weighted column-sum over rows of MT: outv[c][n] += sum_m w[m]*MT[c][m][n] -------
// MODE 1: w = inv(va[m])*vb[m]  ; MODE 2: w = va[m].  64-row strips. ------------------
template<int MODE>
__global__ __launch_bounds__(256)
void k_wsum(const u16* __restrict__ MT, const float* __restrict__ va,
            const float* __restrict__ vb, float* __restrict__ outv){
  __shared__ float w[64];
  const int t = threadIdx.x;
  const int n = blockIdx.x * 256 + t;
  const int m0 = blockIdx.y * 64;
  const int c = blockIdx.z;
  if (t < 64){
    const int m = c*2048 + m0 + t;
    float x;
    if (MODE == 1){ float d = va[m]; x = (d > 0.f ? 1.f/d : 0.f) * vb[m]; }
    else { x = va[m]; }
    w[t] = x;
  }
  __syncthreads();
  const u16* __restrict__ p = MT + (size_t)c*NN + (size_t)m0*2048 + n;
  float s = 0.f;
  #pragma unroll 4
  for (int m=0;m<64;m++)
    s += b2f(p[(size_t)m*2048]) * w[m];
  atomicAdd(&outv[c*2048 + n], s);
}

// ---- fused hw = h@gcn_w then PT[c][d][n] = bf16(rsqrt(max(rowsum,1))*hw[n][d]) ------
__global__ __launch_bounds__(256)
void k_hwpt(const float* __restrict__ h, const float* __restrict__ W,
            const float* __restrict__ rowsum, u16* __restrict__ PT){
  __shared__ float lh[8][256];
  int t = threadIdx.x;
  int n0 = blockIdx.x * 8;
  for (int idx = t; idx < 8*256; idx += 256)
    lh[idx >> 8][idx & 255] = h[(size_t)(n0 + (idx>>8))*256 + (idx&255)];
  __syncthreads();
  int d = t & 127, half = t >> 7;
  float acc[4];
  #pragma unroll
  for (int nn=0;nn<4;nn++) acc[nn] = 0.f;
  for (int k=0;k<256;k++){
    float wv = W[(size_t)k*128 + d];
    #pragma unroll
    for (int nn=0;nn<4;nn++) acc[nn] += lh[half*4+nn][k]*wv;
  }
  #pragma unroll
  for (int c=0;c<2;c++){
    ushort4 o;
    #pragma unroll
    for (int nn=0;nn<4;nn++){
      int n = n0 + half*4 + nn;
      float dv = rsqrtf(fmaxf(rowsum[c*2048 + n], 1.0f));
      ((u16*)&o)[nn] = f2b(dv * acc[nn]);
    }
    *(ushort4*)&PT[((size_t)c*128 + d)*2048 + n0 + half*4] = o;
  }
}

// ------- thin bt-GEMM split-K=8 (2-barrier loop), atomic f32 C: Agg += A @ Bt^T ------
__global__ __launch_bounds__(256, 2)
void k_gemm3(const u16* __restrict__ A, const u16* __restrict__ Bt, float* __restrict__ Agg){
  __shared__ u16 lA[128*64];
  __shared__ u16 lB[128*64];
  const int tid = threadIdx.x;
  const int bm = blockIdx.x, bk = blockIdx.y, cc = blockIdx.z;
  const u16* __restrict__ Ab = A + (size_t)cc*NN + (size_t)(bm*128)*2048 + bk*256;
  const u16* __restrict__ Bb = Bt + (size_t)cc*(128*2048) + bk*256;
  float* __restrict__ Cb = Agg + (size_t)cc*2048*128 + (size_t)(bm*128)*128;
  const int wid = tid >> 6, lane = tid & 63;
  const int wr = wid >> 1, wc = wid & 1;
  const int fl = lane & 15, fk = (lane >> 4) << 3;
  const int srow = (wid << 3) + (lane >> 3);
  const int scol = (lane & 7) << 3;

  f32x4 acc[4][4];
  const f32x4 zero = {0.f,0.f,0.f,0.f};
  #pragma unroll
  for (int i=0;i<4;i++)
    #pragma unroll
    for (int jj=0;jj<4;jj++) acc[i][jj] = zero;

  for (int k0 = 0; k0 < 256; k0 += 64){
    #pragma unroll
    for (int it = 0; it < 4; ++it){
      int r = it*32 + srow;
      __builtin_amdgcn_global_load_lds(
        (const __attribute__((address_space(1))) void*)(Ab + (size_t)r*2048 + k0 + scol),
        (__attribute__((address_space(3))) void*)(&lA[(it*32 + (wid<<3))*64]), 16, 0, 0);
      __builtin_amdgcn_global_load_lds(
        (const __attribute__((address_space(1))) void*)(Bb + (size_t)r*2048 + k0 + scol),
        (__attribute__((address_space(3))) void*)(&lB[(it*32 + (wid<<3))*64]), 16, 0, 0);
    }
    __syncthreads();
    #pragma unroll
    for (int ks = 0; ks < 2; ++ks){
      bf16x8 af[4], bfr[4];
      #pragma unroll
      for (int mi=0;mi<4;mi++)
        af[mi] = *reinterpret_cast<const bf16x8*>(&lA[(wr*64 + mi*16 + fl)*64 + ks*32 + fk]);
      #pragma unroll
      for (int ni=0;ni<4;ni++)
        bfr[ni] = *reinterpret_cast<const bf16x8*>(&lB[(wc*64 + ni*16 + fl)*64 + ks*32 + fk]);
      #pragma unroll
      for (int mi=0;mi<4;mi++)
        #pragma unroll
        for (int ni=0;ni<4;ni++)
          acc[mi][ni] = __builtin_amdgcn_mfma_f32_16x16x32_bf16(af[mi], bfr[ni], acc[mi][ni], 0, 0, 0);
    }
    __syncthreads();
  }
  const int rbase = (lane >> 4) << 2;
  #pragma unroll
  for (int mi=0;mi<4;mi++)
    #pragma unroll
    for (int ni=0;ni<4;ni++)
      #pragma unroll
      for (int r=0;r<4;r++)
        atomicAdd(&Cb[(size_t)(wr*64 + mi*16 + rbase + r)*128 + wc*64 + ni*16 + fl],
                  acc[mi][ni][r]);
}

// ---- Agg f32 [c][2048][128] (+ optional dinv1 row scale) -> transposed bf16 QT ------
template<bool SCALE>
__global__ __launch_bounds__(256)
void k_qt(const float* __restrict__ Agg, const float* __restrict__ deg1,
          u16* __restrict__ QT){
  __shared__ u16 lq[128][36];
  const int t = threadIdx.x;
  const int m0 = blockIdx.x * 32, c = blockIdx.y;
  const int d4 = (t & 31) * 4, mr = t >> 5;
  #pragma unroll
  for (int p4=0; p4<4; ++p4){
    const int m = m0 + p4*8 + mr;
    float4 s = *(const float4*)&Agg[((size_t)c*2048 + m)*128 + d4];
    if (SCALE){
      float dg = deg1[c*2048 + m];
      float di = dg > 0.f ? 1.f/dg : 0.f;
      s.x *= di; s.y *= di; s.z *= di; s.w *= di;
    }
    const int ml = p4*8 + mr;
    lq[d4+0][ml] = f2b(s.x); lq[d4+1][ml] = f2b(s.y);
    lq[d4+2][ml] = f2b(s.z); lq[d4+3][ml] = f2b(s.w);
  }
  __syncthreads();
  const int d = t >> 1, half = t & 1;
  u16* __restrict__ dst = QT + ((size_t)c*128 + d)*2048 + m0 + half*16;
  #pragma unroll
  for (int q=0;q<4;q++){
    ushort4 o;
    o.x = lq[d][half*16 + q*4 + 0];
    o.y = lq[d][half*16 + q*4 + 1];
    o.z = lq[d][half*16 + q*4 + 2];
    o.w = lq[d][half*16 + q*4 + 3];
    *(ushort4*)&dst[q*4] = o;
  }
}

// -------- head: Xc = relu(dinv2[c,m]*agg3 + gb); out = relu(Xc@W1+b1)@W2+b2 ----------
__global__ __launch_bounds__(256)
void k_head(const float* __restrict__ agg3, const float* __restrict__ deg2,
            const float* __restrict__ gb,
            const float* __restrict__ W1, const float* __restrict__ b1,
            const float* __restrict__ W2, const float* __restrict__ b2,
            float* __restrict__ out){
  __shared__ float lx[8][256];
  __shared__ float lt[8][132];
  int t = threadIdx.x;
  int n0 = blockIdx.x * 8;
  for (int idx = t; idx < 512; idx += 256){
    int row = idx >> 6;
    int q = idx & 63;
    int c = q >> 5, d4 = (q & 31) * 4;
    float dg = deg2[c*2048 + n0 + row];
    float di = dg > 0.f ? 1.f/dg : 0.f;
    float4 s = *(const float4*)&agg3[((size_t)c*2048 + n0 + row)*128 + d4];
    const float4 bv = *(const float4*)&gb[d4];
    s.x = fmaxf(s.x*di + bv.x, 0.f); s.y = fmaxf(s.y*di + bv.y, 0.f);
    s.z = fmaxf(s.z*di + bv.z, 0.f); s.w = fmaxf(s.w*di + bv.w, 0.f);
    *(float4*)&lx[row][c*128 + d4] = s;
  }
  __syncthreads();
  int d = t & 127, half = t >> 7;
  float acc[4];
  #pragma unroll
  for (int nn=0;nn<4;nn++) acc[nn] = 0.f;
  for (int k=0;k<256;k++){
    float wv = W1[(size_t)k*128 + d];
    #pragma unroll
    for (int nn=0;nn<4;nn++) acc[nn] += lx[half*4+nn][k]*wv;
  }
  float bb = b1[d];
  #pragma unroll
  for (int nn=0;nn<4;nn++){
    float v = acc[nn] + bb;
    lt[half*4+nn][d] = v > 0.f ? v : 0.f;
  }
  __syncthreads();
  if (t < 128){
    int row = t >> 4, q = t & 15;
    float s = b2[q];
    for (int dd=0; dd<128; dd++) s += lt[row][dd] * W2[(size_t)dd*16 + q];
    out[(size_t)(n0+row)*16 + q] = s;
  }
}

extern "C" void kernel_launch(void* const* d_in, const int* in_sizes, int n_in,
                              void* d_out, int out_size, void* d_ws, size_t ws_size,
                              hipStream_t stream){
  const float* A   = (const float*)d_in[0];
  const float* h   = (const float*)d_in[1];
  const float* w1  = (const float*)d_in[2];
  const float* w2  = (const float*)d_in[3];
  const float* wl  = (const float*)d_in[4];
  const float* gw  = (const float*)d_in[5];
  const float* gb  = (const float*)d_in[6];
  const float* l1w = (const float*)d_in[7];
  const float* l1b = (const float*)d_in[8];
  const float* l2w = (const float*)d_in[9];
  const float* l2b = (const float*)d_in[10];
  float* out = (float*)d_out;
  char* ws = (char*)d_ws;

  const size_t SZ = 2*NN*2;     // 16.78 MB (one bf16 [2][2048][2048])
  const size_t AGG = (size_t)2*2048*128*4;   // 2 MB
  u16*  A1T  = (u16*)(ws);
  u16*  A2T  = (u16*)(ws + 1*SZ);
  u16*  BT   = (u16*)(ws + 2*SZ);
  char* tail = ws + 3*SZ;
  u16*  PT     = (u16*)tail;                      // 1MB
  u16*  Q1T    = (u16*)(tail + 1048576);          // 1MB
  u16*  Q2T    = (u16*)(tail + 2*1048576);        // 1MB
  float* sA1   = (float*)(tail + 3*1048576);      // zeroed region starts here
  float* deg1  = sA1 + 4096;
  float* deg2  = deg1 + 4096;
  float* v1    = deg2 + 4096;
  float* v3    = v1 + 4096;
  float* rowsum= v3 + 4096;
  float* agg1  = rowsum + 4096;                   // 3 x 2MB
  float* agg2  = agg1 + 2*2048*128;
  float* agg3  = agg2 + 2*2048*128;
  const size_t ZBYTES = 6*4096*4 + 3*AGG;

  const size_t TOTAL = 3*SZ + 3*1048576 + ZBYTES;
  if (ws_size < TOTAL){ hipMemsetAsync(d_out, 0, (size_t)out_size*4, stream); return; }

  hipMemsetAsync(sA1, 0, ZBYTES, stream);

  // A -> A1T, A2T, BT + sA1 (colsum A1), deg2 (colsum B)
  k_mix<<<dim3(32,32), 256, 0, stream>>>(A, w1, w2, wl, A1T, A2T, BT, sA1, deg2);
  // merged: deg1 = sA1@A2 (row-dots)  ||  v1 = B@dinv2
  k_post1<<<1536, 256, 0, stream>>>(A2T, BT, sA1, deg2, deg1, v1);
  // rowsum chain: v3 = A2@(dinv1*v1) ; rowsum = A1@v3
  k_wsum<1><<<dim3(8,32,2), 256, 0, stream>>>(A2T, deg1, v1, v3);
  k_wsum<2><<<dim3(8,32,2), 256, 0, stream>>>(A1T, v3, v3, rowsum);
  // features: PT = dout * (h@gcn_w)^T
  k_hwpt<<<256, 256, 0, stream>>>(h, gw, rowsum, PT);
  // agg chain: Q1 = A1^T@P ; Q2 = dinv1*(A2^T@Q1) ; agg3 = B^T@Q2 ; (dinv2 in head)
  k_gemm3<<<dim3(16,8,2), 256, 0, stream>>>(A1T, PT, agg1);
  k_qt<false><<<dim3(64,2), 256, 0, stream>>>(agg1, deg1, Q1T);
  k_gemm3<<<dim3(16,8,2), 256, 0, stream>>>(A2T, Q1T, agg2);
  k_qt<true><<<dim3(64,2), 256, 0, stream>>>(agg2, deg1, Q2T);
  k_gemm3<<<dim3(16,8,2), 256, 0, stream>>>(BT, Q2T, agg3);
  k_head<<<256, 256, 0, stream>>>(agg3, deg2, gb, l1w, l1b, l2w, l2b, out);
}